// Round 9
// baseline (1402.691 us; speedup 1.0000x reference)
//
#include <hip/hip_runtime.h>

// R9: GRU dots restructured scheduler-proof: 96 INDEPENDENT fdot2 products
// (acc=0) + per-gate balanced f32x2 tree reduction (pk_add, depth 5). No
// emission order can create a long dependency chain (R7/R8 showed the
// scheduler wins any ordering fight). 2-step xw prefetch. R8 fences reverted.
// Rest identical to R7.

namespace {

constexpr int B_ = 2, T_ = 2048, E_ = 1024, H_ = 16, HD_ = 64, G3_ = 192, M_ = B_ * T_;
constexpr float SRg = -1.4426950408889634f;  // -log2(e), r/z gates
constexpr float SNg = 2.8853900817779268f;   // 2*log2(e), n gate

typedef _Float16 f16;
typedef _Float16 f16x8 __attribute__((ext_vector_type(8)));
typedef _Float16 f16x4 __attribute__((ext_vector_type(4)));
typedef _Float16 f16x2 __attribute__((ext_vector_type(2)));
typedef float f32x4 __attribute__((ext_vector_type(4)));
typedef float f32x2 __attribute__((ext_vector_type(2)));

__device__ __forceinline__ f32x4 mfma16(f16x8 a, f16x8 b, f32x4 c) {
  return __builtin_amdgcn_mfma_f32_16x16x32_f16(a, b, c, 0, 0, 0);
}

#if __has_builtin(__builtin_amdgcn_fdot2)
__device__ __forceinline__ float fdot2(f16x2 a, f16x2 b, float c) {
  return __builtin_amdgcn_fdot2(a, b, c, false);
}
#else
__device__ __forceinline__ float fdot2(f16x2 a, f16x2 b, float c) {
  return c + (float)a[0] * (float)b[0] + (float)a[1] * (float)b[1];
}
#endif

__device__ __forceinline__ float exp2_(float x) {
#if __has_builtin(__builtin_amdgcn_exp2f)
  return __builtin_amdgcn_exp2f(x);
#else
  return exp2f(x);
#endif
}
__device__ __forceinline__ float rcp_(float x) {
#if __has_builtin(__builtin_amdgcn_rcpf)
  return __builtin_amdgcn_rcpf(x);
#else
  return 1.f / x;
#endif
}

// stage a 128x64 f32 tile -> f16 LDS [128][72]; same thread mapping as f16 path
__device__ __forceinline__ void stage_w_f32(const float* __restrict__ Wf,
                                            f16 (*Bs)[72], int n0, int kt,
                                            int tid) {
#pragma unroll
  for (int it = 0; it < 4; ++it) {
    const int r = it * 32 + (tid >> 3);
    const int cs = (tid & 7) * 8;
    const float* src = Wf + (size_t)(n0 + r) * E_ + kt + cs;
    float4 w0 = *(const float4*)src;
    float4 w1 = *(const float4*)(src + 4);
    f16x8 o = {(f16)w0.x, (f16)w0.y, (f16)w0.z, (f16)w0.w,
               (f16)w1.x, (f16)w1.y, (f16)w1.z, (f16)w1.w};
    *(f16x8*)&Bs[r][cs] = o;
  }
}

// ---------------- prep: v = silu(x)*emb, x_proj pooling, xw = pool16(x)@wih^T
__global__ __launch_bounds__(256) void k_prep(
    const float* __restrict__ x, const int* __restrict__ tok,
    const float* __restrict__ wihq, const float* __restrict__ wihk,
    const float* __restrict__ v_emb,
    f16* __restrict__ vh, f16* __restrict__ aq, f16* __restrict__ ak,
    float* __restrict__ xwq, float* __restrict__ xwk) {
  __shared__ float xs[E_];
  __shared__ float xp[64];
  const int row = blockIdx.x;
  const int b = row >> 11, t = row & (T_ - 1);
  const int tid = threadIdx.x;
  const float* xrow = x + (size_t)row * E_;
  {
    const int tk = tok[row];
    float4 xv = ((const float4*)xrow)[tid];
    ((float4*)xs)[tid] = xv;
    float4 ev = ((const float4*)(v_emb + (size_t)tk * E_))[tid];
    f16x4 o;
    o[0] = (f16)(xv.x / (1.f + __expf(-xv.x)) * ev.x);
    o[1] = (f16)(xv.y / (1.f + __expf(-xv.y)) * ev.y);
    o[2] = (f16)(xv.z / (1.f + __expf(-xv.z)) * ev.z);
    o[3] = (f16)(xv.w / (1.f + __expf(-xv.w)) * ev.w);
    const int e0 = tid * 4;
    const size_t voff = ((size_t)(b * H_ + (e0 >> 6)) * T_ + t) * HD_ + (e0 & 63);
    *(f16x4*)(vh + voff) = o;
  }
  __syncthreads();
  if (tid < 64) {
    float s = 0.f;
#pragma unroll
    for (int j = 0; j < 16; ++j) s += xs[tid * 16 + j];
    xp[tid] = s * (1.f / 16.f);
  }
  for (int i = tid; i < 960; i += 256) {
    int s0 = (i * 1024) / 960;
    int e0 = ((i + 1) * 1024 + 959) / 960;
    float m = xs[s0];
    if (e0 - s0 == 2) m = (m + xs[s0 + 1]) * 0.5f;
    f16 hv = (f16)m;
    aq[(size_t)row * E_ + 64 + i] = hv;
    ak[(size_t)row * E_ + 64 + i] = hv;
  }
  __syncthreads();
  for (int o = tid; o < 2 * G3_; o += 256) {
    const int chain = o / G3_, g = o % G3_;
    const float* wrow = (chain ? wihk : wihq) + (size_t)g * 64;
    float acc = 0.f;
#pragma unroll
    for (int c = 0; c < 16; ++c) {
      float4 wv = *(const float4*)(wrow + c * 4);
      acc += xp[c * 4] * wv.x + xp[c * 4 + 1] * wv.y +
             xp[c * 4 + 2] * wv.z + xp[c * 4 + 3] * wv.w;
    }
    const float sc = (g < 128) ? SRg : SNg;
    (chain ? xwk : xwq)[(size_t)row * G3_ + g] = acc * sc;
  }
}

// ---------------- GRU core: one wave, lane j owns h_j -----------------------
// Scheduler-proof step: independent products + balanced tree reduce per gate.
__device__ __forceinline__ void gru_core(const float* __restrict__ xw,
                                         const float* __restrict__ whh,
                                         f16* __restrict__ a, int lane) {
  __builtin_amdgcn_s_setprio(3);
  f16x2 wr[32], wz[32], wn[32];
#pragma unroll
  for (int i = 0; i < 32; ++i) {
    wr[i] = {(f16)(whh[(size_t)lane * 64 + i] * SRg),
             (f16)(whh[(size_t)lane * 64 + i + 32] * SRg)};
    wz[i] = {(f16)(whh[(size_t)(64 + lane) * 64 + i] * SRg),
             (f16)(whh[(size_t)(64 + lane) * 64 + i + 32] * SRg)};
    wn[i] = {(f16)(whh[(size_t)(128 + lane) * 64 + i] * SNg),
             (f16)(whh[(size_t)(128 + lane) * 64 + i + 32] * SNg)};
  }
  float h = 0.f;
  // 2-step xw prefetch pipeline (covers L3 latency at short step times)
  float xr = xw[lane], xz = xw[64 + lane], xn = xw[128 + lane];
  const float* nx1 = xw + G3_;
  float pr1 = nx1[lane], pz1 = nx1[64 + lane], pn1 = nx1[128 + lane];
  f16* ap = a + lane;
  for (int t = 0; t < T_; ++t) {
    // pack pair (h_l, h_{l+32}) via permlane32_swap (VALU, no LDS)
    const unsigned hu = (unsigned)__builtin_bit_cast(unsigned short, (f16)h);
    int va = (int)hu, vb = (int)hu;
    asm volatile("v_permlane32_swap_b32 %0, %1" : "+v"(va), "+v"(vb));
    const int pk = (int)(hu | ((unsigned)va << 16));
    int hp[32];
#pragma unroll
    for (int i = 0; i < 32; ++i) hp[i] = __builtin_amdgcn_readlane(pk, i);
    // prefetch t+2
    const int tn = (t + 2 < T_) ? t + 2 : T_ - 1;
    const float* nx = xw + (size_t)tn * G3_;
    const float pr2 = nx[lane], pz2 = nx[64 + lane], pn2 = nx[128 + lane];
    // gate r: 32 independent products, f32x2 tree (depth 5)
    float ar, az, an;
    {
      f32x2 u[16];
#pragma unroll
      for (int i = 0; i < 16; ++i) {
        u[i][0] = fdot2(wr[2 * i], __builtin_bit_cast(f16x2, hp[2 * i]), 0.f);
        u[i][1] = fdot2(wr[2 * i + 1], __builtin_bit_cast(f16x2, hp[2 * i + 1]), 0.f);
      }
#pragma unroll
      for (int s2 = 8; s2 >= 1; s2 >>= 1)
#pragma unroll
        for (int i = 0; i < 8; ++i)
          if (i < s2) u[i] = u[i] + u[i + s2];
      ar = u[0][0] + u[0][1] + xr;
    }
    {
      f32x2 u[16];
#pragma unroll
      for (int i = 0; i < 16; ++i) {
        u[i][0] = fdot2(wn[2 * i], __builtin_bit_cast(f16x2, hp[2 * i]), 0.f);
        u[i][1] = fdot2(wn[2 * i + 1], __builtin_bit_cast(f16x2, hp[2 * i + 1]), 0.f);
      }
#pragma unroll
      for (int s2 = 8; s2 >= 1; s2 >>= 1)
#pragma unroll
        for (int i = 0; i < 8; ++i)
          if (i < s2) u[i] = u[i] + u[i + s2];
      an = u[0][0] + u[0][1];
    }
    {
      f32x2 u[16];
#pragma unroll
      for (int i = 0; i < 16; ++i) {
        u[i][0] = fdot2(wz[2 * i], __builtin_bit_cast(f16x2, hp[2 * i]), 0.f);
        u[i][1] = fdot2(wz[2 * i + 1], __builtin_bit_cast(f16x2, hp[2 * i + 1]), 0.f);
      }
#pragma unroll
      for (int s2 = 8; s2 >= 1; s2 >>= 1)
#pragma unroll
        for (int i = 0; i < 8; ++i)
          if (i < s2) u[i] = u[i] + u[i + s2];
      az = u[0][0] + u[0][1] + xz;
    }
    const float r = rcp_(1.f + exp2_(ar));
    const float p2 = fmaf(r, an, xn);
    const float n = fmaf(-2.f, rcp_(1.f + exp2_(p2)), 1.f);  // tanh
    const float z = rcp_(1.f + exp2_(az));
    h = fmaf(z, h - n, n);
    ap[(size_t)t * E_] = (f16)h;
    xr = pr1; xz = pz1; xn = pn1;
    pr1 = pr2; pz1 = pz2; pn1 = pn2;
  }
}

// ---------------- megakernel: GRU (block 0) + QK partial GEMMs (+x) + WO cvt
__global__ __launch_bounds__(256, 1) void k_mega(
    const float* __restrict__ xwq, const float* __restrict__ xwk,
    const float* __restrict__ whhq, const float* __restrict__ whhk,
    f16* __restrict__ aq, f16* __restrict__ ak,
    const float* __restrict__ WQf, const float* __restrict__ WKf,
    const float* __restrict__ x,
    float* __restrict__ QPRE, float* __restrict__ KPRE,
    const float* __restrict__ out_w, f16* __restrict__ WO) {
  __shared__ __align__(16) f16 As[128][72];
  __shared__ __align__(16) f16 Bs[128][72];
  const int bx = blockIdx.x;
  const int tid = threadIdx.x;
  if (bx == 0) {
    const int wid = tid >> 6, lane = tid & 63;
    const int qk = wid >> 1, b = wid & 1;
    const float* xw = (qk ? xwk : xwq) + (size_t)b * T_ * G3_;
    const float* whh = qk ? whhk : whhq;
    f16* a = (qk ? ak : aq) + (size_t)b * T_ * E_;
    gru_core(xw, whh, a, lane);
    return;
  }
  if (bx <= 512) {
    const int bid = bx - 1;
    const int chain = bid >> 8, tile = bid & 255;
    const int m0 = (tile >> 3) * 128, n0 = (tile & 7) * 128;
    const f16* A = chain ? ak : aq;
    const float* Wf = chain ? WKf : WQf;
    float* C = chain ? KPRE : QPRE;
    const int wid = tid >> 6, lane = tid & 63;
    const int wr = wid >> 1, wc = wid & 1;
    const int lg = lane >> 4, lc = lane & 15;
    f32x4 acc[4][4] = {};
    for (int kt = 64; kt < E_; kt += 64) {
#pragma unroll
      for (int it = 0; it < 4; ++it) {
        const int r = it * 32 + (tid >> 3);
        const int cs = (tid & 7) * 8;
        *(f16x8*)&As[r][cs] = *(const f16x8*)(A + (size_t)(m0 + r) * E_ + kt + cs);
      }
      stage_w_f32(Wf, Bs, n0, kt, tid);
      __syncthreads();
      f16x8 af[4][2], bf[4][2];
#pragma unroll
      for (int mi = 0; mi < 4; ++mi)
#pragma unroll
        for (int ks = 0; ks < 2; ++ks) {
          af[mi][ks] = *(const f16x8*)&As[wr * 64 + mi * 16 + lc][ks * 32 + lg * 8];
          bf[mi][ks] = *(const f16x8*)&Bs[wc * 64 + mi * 16 + lc][ks * 32 + lg * 8];
        }
#pragma unroll
      for (int mi = 0; mi < 4; ++mi)
#pragma unroll
        for (int ni = 0; ni < 4; ++ni)
#pragma unroll
          for (int ks = 0; ks < 2; ++ks)
            acc[mi][ni] = mfma16(af[mi][ks], bf[ni][ks], acc[mi][ni]);
      __syncthreads();
    }
#pragma unroll
    for (int mi = 0; mi < 4; ++mi) {
      const int r0 = m0 + wr * 64 + mi * 16 + lg * 4;
#pragma unroll
      for (int ni = 0; ni < 4; ++ni) {
        const int col = n0 + wc * 64 + ni * 16 + lc;
#pragma unroll
        for (int q = 0; q < 4; ++q) {
          const size_t idx = (size_t)(r0 + q) * E_ + col;
          C[idx] = acc[mi][ni][q] + x[idx];
        }
      }
    }
    return;
  }
  {
    const int cb = bx - 513;
    for (int i = cb * 256 + tid; i < E_ * E_ / 4; i += 8 * 256) {
      float4 v = ((const float4*)out_w)[i];
      f16x4 o = {(f16)v.x, (f16)v.y, (f16)v.z, (f16)v.w};
      *(f16x4*)(WO + (size_t)i * 4) = o;
    }
  }
}

// ---------------- fix: C += A[:,0:64] @ W[:,0:64]^T -------------------------
__global__ __launch_bounds__(256) void k_fix(
    const f16* __restrict__ aq, const f16* __restrict__ ak,
    const float* __restrict__ WQf, const float* __restrict__ WKf,
    float* __restrict__ QPRE, float* __restrict__ KPRE) {
  __shared__ __align__(16) f16 As[128][72];
  __shared__ __align__(16) f16 Bs[128][72];
  const int chain = blockIdx.z;
  const f16* A = chain ? ak : aq;
  const float* Wf = chain ? WKf : WQf;
  float* C = chain ? KPRE : QPRE;
  const int m0 = blockIdx.x * 128, n0 = blockIdx.y * 128;
  const int tid = threadIdx.x;
  const int wid = tid >> 6, lane = tid & 63;
  const int wr = wid >> 1, wc = wid & 1;
  const int lg = lane >> 4, lc = lane & 15;
#pragma unroll
  for (int it = 0; it < 4; ++it) {
    const int r = it * 32 + (tid >> 3);
    const int cs = (tid & 7) * 8;
    *(f16x8*)&As[r][cs] = *(const f16x8*)(A + (size_t)(m0 + r) * E_ + cs);
  }
  stage_w_f32(Wf, Bs, n0, 0, tid);
  __syncthreads();
  f32x4 acc[4][4] = {};
  f16x8 af[4][2], bf[4][2];
#pragma unroll
  for (int mi = 0; mi < 4; ++mi)
#pragma unroll
    for (int ks = 0; ks < 2; ++ks) {
      af[mi][ks] = *(const f16x8*)&As[wr * 64 + mi * 16 + lc][ks * 32 + lg * 8];
      bf[mi][ks] = *(const f16x8*)&Bs[wc * 64 + mi * 16 + lc][ks * 32 + lg * 8];
    }
#pragma unroll
  for (int mi = 0; mi < 4; ++mi)
#pragma unroll
    for (int ni = 0; ni < 4; ++ni)
#pragma unroll
      for (int ks = 0; ks < 2; ++ks)
        acc[mi][ni] = mfma16(af[mi][ks], bf[ni][ks], acc[mi][ni]);
#pragma unroll
  for (int mi = 0; mi < 4; ++mi) {
    const int r0 = m0 + wr * 64 + mi * 16 + lg * 4;
#pragma unroll
    for (int ni = 0; ni < 4; ++ni) {
      const int col = n0 + wc * 64 + ni * 16 + lc;
#pragma unroll
      for (int q = 0; q < 4; ++q) {
        const size_t idx = (size_t)(r0 + q) * E_ + col;
        C[idx] += acc[mi][ni][q];
      }
    }
  }
}

// ---------------- LayerNorm (both chains), write f16 in [B,H,T,HD] ---------
__global__ __launch_bounds__(256) void k_ln(
    const float* __restrict__ qpre, const float* __restrict__ kpre,
    const float* __restrict__ qw, const float* __restrict__ qb,
    const float* __restrict__ kw, const float* __restrict__ kb,
    f16* __restrict__ qh, f16* __restrict__ kh) {
  const int chain = blockIdx.y;
  const float* pre = chain ? kpre : qpre;
  const float* gw = chain ? kw : qw;
  const float* gb = chain ? kb : qb;
  f16* outp = chain ? kh : qh;
  const int row = blockIdx.x;
  const int tid = threadIdx.x;
  const float4 v = ((const float4*)(pre + (size_t)row * E_))[tid];
  float s = v.x + v.y + v.z + v.w;
  float s2 = v.x * v.x + v.y * v.y + v.z * v.z + v.w * v.w;
#pragma unroll
  for (int off = 32; off; off >>= 1) {
    s += __shfl_xor(s, off);
    s2 += __shfl_xor(s2, off);
  }
  __shared__ float red[8];
  const int wid = tid >> 6, lane = tid & 63;
  if (!lane) { red[wid] = s; red[4 + wid] = s2; }
  __syncthreads();
  s = red[0] + red[1] + red[2] + red[3];
  s2 = red[4] + red[5] + red[6] + red[7];
  const float mu = s * (1.f / E_);
  const float inv = rsqrtf(s2 * (1.f / E_) - mu * mu + 1e-5f);
  const float4 w4 = ((const float4*)gw)[tid];
  const float4 b4 = ((const float4*)gb)[tid];
  const int e0 = tid * 4;
  f16x4 o;
  o[0] = (f16)((v.x - mu) * inv * w4.x + b4.x);
  o[1] = (f16)((v.y - mu) * inv * w4.y + b4.y);
  o[2] = (f16)((v.z - mu) * inv * w4.z + b4.z);
  o[3] = (f16)((v.w - mu) * inv * w4.w + b4.w);
  const int b = row >> 11, t = row & (T_ - 1);
  const size_t off2 = ((size_t)(b * H_ + (e0 >> 6)) * T_ + t) * HD_ + (e0 & 63);
  *(f16x4*)(outp + off2) = o;
}

// ---------------- flash attention: causal, scores*2/sqrt(64) = *0.25 -------
__global__ __launch_bounds__(256) void k_attn(const f16* __restrict__ Q,
                                              const f16* __restrict__ K,
                                              const f16* __restrict__ V,
                                              f16* __restrict__ AO) {
  __shared__ __align__(16) f16 Kt[64][72];
  __shared__ __align__(16) f16 Vt[64][72];
  __shared__ __align__(16) f16 Ps[4][16][72];
  const int qi = blockIdx.x, bh = blockIdx.y;
  const int b = bh >> 4, h = bh & 15;
  const int tid = threadIdx.x, wid = tid >> 6, lane = tid & 63;
  const int lg = lane >> 4, lc = lane & 15;
  const size_t hbase = (size_t)bh * T_ * HD_;
  const int qb = qi * 64;
  f16x8 qf[2];
  {
    const int qrow = qb + wid * 16 + lc;
#pragma unroll
    for (int ks = 0; ks < 2; ++ks)
      qf[ks] = *(const f16x8*)(Q + hbase + (size_t)qrow * HD_ + ks * 32 + lg * 8);
  }
  f32x4 o[4] = {};
  float m_run[4] = {-1e30f, -1e30f, -1e30f, -1e30f};
  float l_run[4] = {};
  const int qrow_d = qb + wid * 16 + lg * 4;
  for (int kt = 0; kt <= qi; ++kt) {
    {
      const int r = tid >> 2, cs = (tid & 3) * 16;
      const f16* ksrc = K + hbase + (size_t)(kt * 64 + r) * HD_ + cs;
      *(f16x8*)&Kt[r][cs] = *(const f16x8*)ksrc;
      *(f16x8*)&Kt[r][cs + 8] = *(const f16x8*)(ksrc + 8);
      const f16* vsrc = V + hbase + (size_t)(kt * 64 + lane) * HD_ + wid * 16;
      f16x8 va = *(const f16x8*)vsrc;
      f16x8 vb = *(const f16x8*)(vsrc + 8);
#pragma unroll
      for (int u = 0; u < 8; ++u) {
        Vt[wid * 16 + u][lane] = va[u];
        Vt[wid * 16 + 8 + u][lane] = vb[u];
      }
    }
    __syncthreads();
    f32x4 s[4] = {};
#pragma unroll
    for (int nt = 0; nt < 4; ++nt)
#pragma unroll
      for (int ks = 0; ks < 2; ++ks) {
        f16x8 kf = *(const f16x8*)&Kt[nt * 16 + lc][ks * 32 + lg * 8];
        s[nt] = mfma16(qf[ks], kf, s[nt]);
      }
    const bool diag = (kt == qi);
#pragma unroll
    for (int nt = 0; nt < 4; ++nt) {
      const int colg = kt * 64 + nt * 16 + lc;
#pragma unroll
      for (int r = 0; r < 4; ++r) {
        float v = s[nt][r] * 0.25f;
        if (diag && colg > qrow_d + r) v = -1e30f;
        s[nt][r] = v;
      }
    }
    float scalev[4];
#pragma unroll
    for (int r = 0; r < 4; ++r) {
      float m = fmaxf(fmaxf(s[0][r], s[1][r]), fmaxf(s[2][r], s[3][r]));
#pragma unroll
      for (int of = 1; of < 16; of <<= 1) m = fmaxf(m, __shfl_xor(m, of));
      const float mn = fmaxf(m_run[r], m);
      scalev[r] = __expf(m_run[r] - mn);
      m_run[r] = mn;
    }
    float ladd[4] = {};
#pragma unroll
    for (int nt = 0; nt < 4; ++nt)
#pragma unroll
      for (int r = 0; r < 4; ++r) {
        const float p = __expf(s[nt][r] - m_run[r]);
        s[nt][r] = p;
        ladd[r] += p;
      }
#pragma unroll
    for (int r = 0; r < 4; ++r) {
      float la = ladd[r];
#pragma unroll
      for (int of = 1; of < 16; of <<= 1) la += __shfl_xor(la, of);
      l_run[r] = l_run[r] * scalev[r] + la;
      o[0][r] *= scalev[r];
      o[1][r] *= scalev[r];
      o[2][r] *= scalev[r];
      o[3][r] *= scalev[r];
    }
#pragma unroll
    for (int nt = 0; nt < 4; ++nt)
#pragma unroll
      for (int r = 0; r < 4; ++r)
        Ps[wid][lg * 4 + r][nt * 16 + lc] = (f16)s[nt][r];
    f16x8 pf[2];
#pragma unroll
    for (int ks = 0; ks < 2; ++ks)
      pf[ks] = *(const f16x8*)&Ps[wid][lc][ks * 32 + lg * 8];
#pragma unroll
    for (int nt = 0; nt < 4; ++nt)
#pragma unroll
      for (int ks = 0; ks < 2; ++ks) {
        f16x8 vf = *(const f16x8*)&Vt[nt * 16 + lc][ks * 32 + lg * 8];
        o[nt] = mfma16(pf[ks], vf, o[nt]);
      }
    __syncthreads();
  }
#pragma unroll
  for (int nt = 0; nt < 4; ++nt)
#pragma unroll
    for (int r = 0; r < 4; ++r) {
      const float val = o[nt][r] / l_run[r];
      const int qrow = qrow_d + r;
      AO[((size_t)(b * T_ + qrow)) * E_ + h * HD_ + nt * 16 + lc] = (f16)val;
    }
}

// ---------------- out GEMM: C = A @ WO^T + bias -----------------------------
__global__ __launch_bounds__(256) void k_gemm_out(
    const f16* __restrict__ A, const f16* __restrict__ W,
    const float* __restrict__ bias, float* __restrict__ C) {
  __shared__ __align__(16) f16 As[128][72];
  __shared__ __align__(16) f16 Bs[128][72];
  const int m0 = blockIdx.x * 128, n0 = blockIdx.y * 128;
  const int tid = threadIdx.x;
  const int wid = tid >> 6, lane = tid & 63;
  const int wr = wid >> 1, wc = wid & 1;
  const int lg = lane >> 4, lc = lane & 15;
  f32x4 acc[4][4] = {};
  for (int kt = 0; kt < E_; kt += 64) {
#pragma unroll
    for (int it = 0; it < 4; ++it) {
      const int r = it * 32 + (tid >> 3);
      const int cs = (tid & 7) * 8;
      *(f16x8*)&As[r][cs] = *(const f16x8*)(A + (size_t)(m0 + r) * E_ + kt + cs);
      *(f16x8*)&Bs[r][cs] = *(const f16x8*)(W + (size_t)(n0 + r) * E_ + kt + cs);
    }
    __syncthreads();
    f16x8 af[4][2], bf[4][2];
#pragma unroll
    for (int mi = 0; mi < 4; ++mi)
#pragma unroll
      for (int ks = 0; ks < 2; ++ks) {
        af[mi][ks] = *(const f16x8*)&As[wr * 64 + mi * 16 + lc][ks * 32 + lg * 8];
        bf[mi][ks] = *(const f16x8*)&Bs[wc * 64 + mi * 16 + lc][ks * 32 + lg * 8];
      }
#pragma unroll
    for (int mi = 0; mi < 4; ++mi)
#pragma unroll
      for (int ni = 0; ni < 4; ++ni)
#pragma unroll
        for (int ks = 0; ks < 2; ++ks)
          acc[mi][ni] = mfma16(af[mi][ks], bf[ni][ks], acc[mi][ni]);
    __syncthreads();
  }
#pragma unroll
  for (int mi = 0; mi < 4; ++mi) {
    const int r0 = m0 + wr * 64 + mi * 16 + lg * 4;
#pragma unroll
    for (int ni = 0; ni < 4; ++ni) {
      const int col = n0 + wc * 64 + ni * 16 + lc;
      const float bv = bias[col];
#pragma unroll
      for (int q = 0; q < 4; ++q)
        C[(size_t)(r0 + q) * E_ + col] = acc[mi][ni][q] + bv;
    }
  }
}

}  // namespace

extern "C" void kernel_launch(void* const* d_in, const int* in_sizes, int n_in,
                              void* d_out, int out_size, void* d_ws, size_t ws_size,
                              hipStream_t stream) {
  (void)in_sizes; (void)n_in; (void)out_size; (void)ws_size;
  const float* x      = (const float*)d_in[0];
  const int*   tok    = (const int*)d_in[1];
  const float* q_wih  = (const float*)d_in[2];
  const float* q_whh  = (const float*)d_in[3];
  const float* q_lin  = (const float*)d_in[4];
  const float* k_wih  = (const float*)d_in[5];
  const float* k_whh  = (const float*)d_in[6];
  const float* k_lin  = (const float*)d_in[7];
  const float* v_emb  = (const float*)d_in[8];
  const float* q_ln_w = (const float*)d_in[9];
  const float* q_ln_b = (const float*)d_in[10];
  const float* k_ln_w = (const float*)d_in[11];
  const float* k_ln_b = (const float*)d_in[12];
  const float* out_w  = (const float*)d_in[13];
  const float* out_b  = (const float*)d_in[14];
  float* outp = (float*)d_out;

  char* ws = (char*)d_ws;
  size_t off = 0;
  auto take = [&](size_t bytes) -> void* {
    void* p = ws + off;
    off += (bytes + 255) & ~(size_t)255;
    return p;
  };
  f16* WO   = (f16*)take((size_t)E_ * E_ * 2);
  f16* AQ   = (f16*)take((size_t)M_ * E_ * 2);
  f16* AK   = (f16*)take((size_t)M_ * E_ * 2);
  f16* VH   = (f16*)take((size_t)M_ * E_ * 2);
  f16* QH   = (f16*)take((size_t)M_ * E_ * 2);
  f16* KH   = (f16*)take((size_t)M_ * E_ * 2);
  f16* AO   = (f16*)take((size_t)M_ * E_ * 2);
  float* XWQ  = (float*)take((size_t)M_ * G3_ * 4);
  float* XWK  = (float*)take((size_t)M_ * G3_ * 4);
  float* QPRE = (float*)take((size_t)M_ * E_ * 4);
  float* KPRE = (float*)take((size_t)M_ * E_ * 4);

  k_prep<<<dim3(M_), dim3(256), 0, stream>>>(x, tok, q_wih, k_wih, v_emb, VH, AQ, AK, XWQ, XWK);

  k_mega<<<dim3(521), dim3(256), 0, stream>>>(XWQ, XWK, q_whh, k_whh, AQ, AK,
                                              q_lin, k_lin, x, QPRE, KPRE, out_w, WO);

  k_fix<<<dim3(M_ / 128, E_ / 128, 2), dim3(256), 0, stream>>>(AQ, AK, q_lin, k_lin, QPRE, KPRE);
  k_ln<<<dim3(M_, 2), dim3(256), 0, stream>>>(QPRE, KPRE, q_ln_w, q_ln_b, k_ln_w, k_ln_b, QH, KH);

  k_attn<<<dim3(T_ / 64, B_ * H_), dim3(256), 0, stream>>>(QH, KH, VH, AO);
  k_gemm_out<<<dim3(M_ / 128, E_ / 128), dim3(256), 0, stream>>>(AO, WO, out_b, outp);
}

// Round 10
// 940.507 us; speedup vs baseline: 1.4914x; 1.4914x over previous
//
#include <hip/hip_runtime.h>

// R10: single-variable test of the fdot2-latency model. gru_core == R7 except
// each gate dot uses 4 independent accumulators (8 links x ~24cy = 192 < issue)
// in natural chain-major order, NO sched fences (R8's confound), R7's 1-step
// prefetch. All other kernels identical to R7 (best measured: 657us k_mega).

namespace {

constexpr int B_ = 2, T_ = 2048, E_ = 1024, H_ = 16, HD_ = 64, G3_ = 192, M_ = B_ * T_;
constexpr float SRg = -1.4426950408889634f;  // -log2(e), r/z gates
constexpr float SNg = 2.8853900817779268f;   // 2*log2(e), n gate

typedef _Float16 f16;
typedef _Float16 f16x8 __attribute__((ext_vector_type(8)));
typedef _Float16 f16x4 __attribute__((ext_vector_type(4)));
typedef _Float16 f16x2 __attribute__((ext_vector_type(2)));
typedef float f32x4 __attribute__((ext_vector_type(4)));

__device__ __forceinline__ f32x4 mfma16(f16x8 a, f16x8 b, f32x4 c) {
  return __builtin_amdgcn_mfma_f32_16x16x32_f16(a, b, c, 0, 0, 0);
}

#if __has_builtin(__builtin_amdgcn_fdot2)
__device__ __forceinline__ float fdot2(f16x2 a, f16x2 b, float c) {
  return __builtin_amdgcn_fdot2(a, b, c, false);
}
#else
__device__ __forceinline__ float fdot2(f16x2 a, f16x2 b, float c) {
  return c + (float)a[0] * (float)b[0] + (float)a[1] * (float)b[1];
}
#endif

__device__ __forceinline__ float exp2_(float x) {
#if __has_builtin(__builtin_amdgcn_exp2f)
  return __builtin_amdgcn_exp2f(x);
#else
  return exp2f(x);
#endif
}
__device__ __forceinline__ float rcp_(float x) {
#if __has_builtin(__builtin_amdgcn_rcpf)
  return __builtin_amdgcn_rcpf(x);
#else
  return 1.f / x;
#endif
}

// stage a 128x64 f32 tile -> f16 LDS [128][72]; same thread mapping as f16 path
__device__ __forceinline__ void stage_w_f32(const float* __restrict__ Wf,
                                            f16 (*Bs)[72], int n0, int kt,
                                            int tid) {
#pragma unroll
  for (int it = 0; it < 4; ++it) {
    const int r = it * 32 + (tid >> 3);
    const int cs = (tid & 7) * 8;
    const float* src = Wf + (size_t)(n0 + r) * E_ + kt + cs;
    float4 w0 = *(const float4*)src;
    float4 w1 = *(const float4*)(src + 4);
    f16x8 o = {(f16)w0.x, (f16)w0.y, (f16)w0.z, (f16)w0.w,
               (f16)w1.x, (f16)w1.y, (f16)w1.z, (f16)w1.w};
    *(f16x8*)&Bs[r][cs] = o;
  }
}

// ---------------- prep: v = silu(x)*emb, x_proj pooling, xw = pool16(x)@wih^T
__global__ __launch_bounds__(256) void k_prep(
    const float* __restrict__ x, const int* __restrict__ tok,
    const float* __restrict__ wihq, const float* __restrict__ wihk,
    const float* __restrict__ v_emb,
    f16* __restrict__ vh, f16* __restrict__ aq, f16* __restrict__ ak,
    float* __restrict__ xwq, float* __restrict__ xwk) {
  __shared__ float xs[E_];
  __shared__ float xp[64];
  const int row = blockIdx.x;
  const int b = row >> 11, t = row & (T_ - 1);
  const int tid = threadIdx.x;
  const float* xrow = x + (size_t)row * E_;
  {
    const int tk = tok[row];
    float4 xv = ((const float4*)xrow)[tid];
    ((float4*)xs)[tid] = xv;
    float4 ev = ((const float4*)(v_emb + (size_t)tk * E_))[tid];
    f16x4 o;
    o[0] = (f16)(xv.x / (1.f + __expf(-xv.x)) * ev.x);
    o[1] = (f16)(xv.y / (1.f + __expf(-xv.y)) * ev.y);
    o[2] = (f16)(xv.z / (1.f + __expf(-xv.z)) * ev.z);
    o[3] = (f16)(xv.w / (1.f + __expf(-xv.w)) * ev.w);
    const int e0 = tid * 4;
    const size_t voff = ((size_t)(b * H_ + (e0 >> 6)) * T_ + t) * HD_ + (e0 & 63);
    *(f16x4*)(vh + voff) = o;
  }
  __syncthreads();
  if (tid < 64) {
    float s = 0.f;
#pragma unroll
    for (int j = 0; j < 16; ++j) s += xs[tid * 16 + j];
    xp[tid] = s * (1.f / 16.f);
  }
  for (int i = tid; i < 960; i += 256) {
    int s0 = (i * 1024) / 960;
    int e0 = ((i + 1) * 1024 + 959) / 960;
    float m = xs[s0];
    if (e0 - s0 == 2) m = (m + xs[s0 + 1]) * 0.5f;
    f16 hv = (f16)m;
    aq[(size_t)row * E_ + 64 + i] = hv;
    ak[(size_t)row * E_ + 64 + i] = hv;
  }
  __syncthreads();
  for (int o = tid; o < 2 * G3_; o += 256) {
    const int chain = o / G3_, g = o % G3_;
    const float* wrow = (chain ? wihk : wihq) + (size_t)g * 64;
    float acc = 0.f;
#pragma unroll
    for (int c = 0; c < 16; ++c) {
      float4 wv = *(const float4*)(wrow + c * 4);
      acc += xp[c * 4] * wv.x + xp[c * 4 + 1] * wv.y +
             xp[c * 4 + 2] * wv.z + xp[c * 4 + 3] * wv.w;
    }
    const float sc = (g < 128) ? SRg : SNg;
    (chain ? xwk : xwq)[(size_t)row * G3_ + g] = acc * sc;
  }
}

// ---------------- GRU core: one wave, lane j owns h_j -----------------------
// R7 structure; only change: 4 accumulators per gate (breaks the ~24cy fdot2
// dependent chain: 8 links/acc), chain-major natural order, no fences.
__device__ __forceinline__ void gru_core(const float* __restrict__ xw,
                                         const float* __restrict__ whh,
                                         f16* __restrict__ a, int lane) {
  __builtin_amdgcn_s_setprio(3);
  f16x2 wr[32], wz[32], wn[32];
#pragma unroll
  for (int i = 0; i < 32; ++i) {
    wr[i] = {(f16)(whh[(size_t)lane * 64 + i] * SRg),
             (f16)(whh[(size_t)lane * 64 + i + 32] * SRg)};
    wz[i] = {(f16)(whh[(size_t)(64 + lane) * 64 + i] * SRg),
             (f16)(whh[(size_t)(64 + lane) * 64 + i + 32] * SRg)};
    wn[i] = {(f16)(whh[(size_t)(128 + lane) * 64 + i] * SNg),
             (f16)(whh[(size_t)(128 + lane) * 64 + i + 32] * SNg)};
  }
  float h = 0.f;
  float xr = xw[lane], xz = xw[64 + lane], xn = xw[128 + lane];
  f16* ap = a + lane;
  for (int t = 0; t < T_; ++t) {
    // pack pair (h_l, h_{l+32}) via permlane32_swap (VALU, no LDS)
    const unsigned hu = (unsigned)__builtin_bit_cast(unsigned short, (f16)h);
    int va = (int)hu, vb = (int)hu;
    asm volatile("v_permlane32_swap_b32 %0, %1" : "+v"(va), "+v"(vb));
    const int pk = (int)(hu | ((unsigned)va << 16));
    // prefetch next step's xw — consumed after the dots
    const int tn = (t + 1 < T_) ? t + 1 : t;
    const float* nx = xw + (size_t)tn * G3_;
    const float nxr = nx[lane], nxz = nx[64 + lane], nxn = nx[128 + lane];
    // broadcast: 32 readlanes batched
    int hp[32];
#pragma unroll
    for (int i = 0; i < 32; ++i) hp[i] = __builtin_amdgcn_readlane(pk, i);
    // gate dots: 4 accumulators per gate, chain-major
    float ar0 = xr, ar1 = 0.f, ar2 = 0.f, ar3 = 0.f;
#pragma unroll
    for (int i = 0; i < 8; ++i) {
      ar0 = fdot2(wr[4 * i + 0], __builtin_bit_cast(f16x2, hp[4 * i + 0]), ar0);
      ar1 = fdot2(wr[4 * i + 1], __builtin_bit_cast(f16x2, hp[4 * i + 1]), ar1);
      ar2 = fdot2(wr[4 * i + 2], __builtin_bit_cast(f16x2, hp[4 * i + 2]), ar2);
      ar3 = fdot2(wr[4 * i + 3], __builtin_bit_cast(f16x2, hp[4 * i + 3]), ar3);
    }
    float an0 = 0.f, an1 = 0.f, an2 = 0.f, an3 = 0.f;
#pragma unroll
    for (int i = 0; i < 8; ++i) {
      an0 = fdot2(wn[4 * i + 0], __builtin_bit_cast(f16x2, hp[4 * i + 0]), an0);
      an1 = fdot2(wn[4 * i + 1], __builtin_bit_cast(f16x2, hp[4 * i + 1]), an1);
      an2 = fdot2(wn[4 * i + 2], __builtin_bit_cast(f16x2, hp[4 * i + 2]), an2);
      an3 = fdot2(wn[4 * i + 3], __builtin_bit_cast(f16x2, hp[4 * i + 3]), an3);
    }
    float az0 = xz, az1 = 0.f, az2 = 0.f, az3 = 0.f;
#pragma unroll
    for (int i = 0; i < 8; ++i) {
      az0 = fdot2(wz[4 * i + 0], __builtin_bit_cast(f16x2, hp[4 * i + 0]), az0);
      az1 = fdot2(wz[4 * i + 1], __builtin_bit_cast(f16x2, hp[4 * i + 1]), az1);
      az2 = fdot2(wz[4 * i + 2], __builtin_bit_cast(f16x2, hp[4 * i + 2]), az2);
      az3 = fdot2(wz[4 * i + 3], __builtin_bit_cast(f16x2, hp[4 * i + 3]), az3);
    }
    const float ar = (ar0 + ar1) + (ar2 + ar3);
    const float an = (an0 + an1) + (an2 + an3);
    const float az = (az0 + az1) + (az2 + az3);
    const float r = rcp_(1.f + exp2_(ar));
    const float p2 = fmaf(r, an, xn);
    const float n = fmaf(-2.f, rcp_(1.f + exp2_(p2)), 1.f);  // tanh
    const float z = rcp_(1.f + exp2_(az));
    h = fmaf(z, h - n, n);
    ap[(size_t)t * E_] = (f16)h;
    xr = nxr; xz = nxz; xn = nxn;
  }
}

// ---------------- megakernel: GRU (block 0) + QK partial GEMMs (+x) + WO cvt
__global__ __launch_bounds__(256, 1) void k_mega(
    const float* __restrict__ xwq, const float* __restrict__ xwk,
    const float* __restrict__ whhq, const float* __restrict__ whhk,
    f16* __restrict__ aq, f16* __restrict__ ak,
    const float* __restrict__ WQf, const float* __restrict__ WKf,
    const float* __restrict__ x,
    float* __restrict__ QPRE, float* __restrict__ KPRE,
    const float* __restrict__ out_w, f16* __restrict__ WO) {
  __shared__ __align__(16) f16 As[128][72];
  __shared__ __align__(16) f16 Bs[128][72];
  const int bx = blockIdx.x;
  const int tid = threadIdx.x;
  if (bx == 0) {
    const int wid = tid >> 6, lane = tid & 63;
    const int qk = wid >> 1, b = wid & 1;
    const float* xw = (qk ? xwk : xwq) + (size_t)b * T_ * G3_;
    const float* whh = qk ? whhk : whhq;
    f16* a = (qk ? ak : aq) + (size_t)b * T_ * E_;
    gru_core(xw, whh, a, lane);
    return;
  }
  if (bx <= 512) {
    const int bid = bx - 1;
    const int chain = bid >> 8, tile = bid & 255;
    const int m0 = (tile >> 3) * 128, n0 = (tile & 7) * 128;
    const f16* A = chain ? ak : aq;
    const float* Wf = chain ? WKf : WQf;
    float* C = chain ? KPRE : QPRE;
    const int wid = tid >> 6, lane = tid & 63;
    const int wr = wid >> 1, wc = wid & 1;
    const int lg = lane >> 4, lc = lane & 15;
    f32x4 acc[4][4] = {};
    for (int kt = 64; kt < E_; kt += 64) {
#pragma unroll
      for (int it = 0; it < 4; ++it) {
        const int r = it * 32 + (tid >> 3);
        const int cs = (tid & 7) * 8;
        *(f16x8*)&As[r][cs] = *(const f16x8*)(A + (size_t)(m0 + r) * E_ + kt + cs);
      }
      stage_w_f32(Wf, Bs, n0, kt, tid);
      __syncthreads();
      f16x8 af[4][2], bf[4][2];
#pragma unroll
      for (int mi = 0; mi < 4; ++mi)
#pragma unroll
        for (int ks = 0; ks < 2; ++ks) {
          af[mi][ks] = *(const f16x8*)&As[wr * 64 + mi * 16 + lc][ks * 32 + lg * 8];
          bf[mi][ks] = *(const f16x8*)&Bs[wc * 64 + mi * 16 + lc][ks * 32 + lg * 8];
        }
#pragma unroll
      for (int mi = 0; mi < 4; ++mi)
#pragma unroll
        for (int ni = 0; ni < 4; ++ni)
#pragma unroll
          for (int ks = 0; ks < 2; ++ks)
            acc[mi][ni] = mfma16(af[mi][ks], bf[ni][ks], acc[mi][ni]);
      __syncthreads();
    }
#pragma unroll
    for (int mi = 0; mi < 4; ++mi) {
      const int r0 = m0 + wr * 64 + mi * 16 + lg * 4;
#pragma unroll
      for (int ni = 0; ni < 4; ++ni) {
        const int col = n0 + wc * 64 + ni * 16 + lc;
#pragma unroll
        for (int q = 0; q < 4; ++q) {
          const size_t idx = (size_t)(r0 + q) * E_ + col;
          C[idx] = acc[mi][ni][q] + x[idx];
        }
      }
    }
    return;
  }
  {
    const int cb = bx - 513;
    for (int i = cb * 256 + tid; i < E_ * E_ / 4; i += 8 * 256) {
      float4 v = ((const float4*)out_w)[i];
      f16x4 o = {(f16)v.x, (f16)v.y, (f16)v.z, (f16)v.w};
      *(f16x4*)(WO + (size_t)i * 4) = o;
    }
  }
}

// ---------------- fix: C += A[:,0:64] @ W[:,0:64]^T -------------------------
__global__ __launch_bounds__(256) void k_fix(
    const f16* __restrict__ aq, const f16* __restrict__ ak,
    const float* __restrict__ WQf, const float* __restrict__ WKf,
    float* __restrict__ QPRE, float* __restrict__ KPRE) {
  __shared__ __align__(16) f16 As[128][72];
  __shared__ __align__(16) f16 Bs[128][72];
  const int chain = blockIdx.z;
  const f16* A = chain ? ak : aq;
  const float* Wf = chain ? WKf : WQf;
  float* C = chain ? KPRE : QPRE;
  const int m0 = blockIdx.x * 128, n0 = blockIdx.y * 128;
  const int tid = threadIdx.x;
  const int wid = tid >> 6, lane = tid & 63;
  const int wr = wid >> 1, wc = wid & 1;
  const int lg = lane >> 4, lc = lane & 15;
#pragma unroll
  for (int it = 0; it < 4; ++it) {
    const int r = it * 32 + (tid >> 3);
    const int cs = (tid & 7) * 8;
    *(f16x8*)&As[r][cs] = *(const f16x8*)(A + (size_t)(m0 + r) * E_ + cs);
  }
  stage_w_f32(Wf, Bs, n0, 0, tid);
  __syncthreads();
  f32x4 acc[4][4] = {};
  f16x8 af[4][2], bf[4][2];
#pragma unroll
  for (int mi = 0; mi < 4; ++mi)
#pragma unroll
    for (int ks = 0; ks < 2; ++ks) {
      af[mi][ks] = *(const f16x8*)&As[wr * 64 + mi * 16 + lc][ks * 32 + lg * 8];
      bf[mi][ks] = *(const f16x8*)&Bs[wc * 64 + mi * 16 + lc][ks * 32 + lg * 8];
    }
#pragma unroll
  for (int mi = 0; mi < 4; ++mi)
#pragma unroll
    for (int ni = 0; ni < 4; ++ni)
#pragma unroll
      for (int ks = 0; ks < 2; ++ks)
        acc[mi][ni] = mfma16(af[mi][ks], bf[ni][ks], acc[mi][ni]);
#pragma unroll
  for (int mi = 0; mi < 4; ++mi) {
    const int r0 = m0 + wr * 64 + mi * 16 + lg * 4;
#pragma unroll
    for (int ni = 0; ni < 4; ++ni) {
      const int col = n0 + wc * 64 + ni * 16 + lc;
#pragma unroll
      for (int q = 0; q < 4; ++q) {
        const size_t idx = (size_t)(r0 + q) * E_ + col;
        C[idx] += acc[mi][ni][q];
      }
    }
  }
}

// ---------------- LayerNorm (both chains), write f16 in [B,H,T,HD] ---------
__global__ __launch_bounds__(256) void k_ln(
    const float* __restrict__ qpre, const float* __restrict__ kpre,
    const float* __restrict__ qw, const float* __restrict__ qb,
    const float* __restrict__ kw, const float* __restrict__ kb,
    f16* __restrict__ qh, f16* __restrict__ kh) {
  const int chain = blockIdx.y;
  const float* pre = chain ? kpre : qpre;
  const float* gw = chain ? kw : qw;
  const float* gb = chain ? kb : qb;
  f16* outp = chain ? kh : qh;
  const int row = blockIdx.x;
  const int tid = threadIdx.x;
  const float4 v = ((const float4*)(pre + (size_t)row * E_))[tid];
  float s = v.x + v.y + v.z + v.w;
  float s2 = v.x * v.x + v.y * v.y + v.z * v.z + v.w * v.w;
#pragma unroll
  for (int off = 32; off; off >>= 1) {
    s += __shfl_xor(s, off);
    s2 += __shfl_xor(s2, off);
  }
  __shared__ float red[8];
  const int wid = tid >> 6, lane = tid & 63;
  if (!lane) { red[wid] = s; red[4 + wid] = s2; }
  __syncthreads();
  s = red[0] + red[1] + red[2] + red[3];
  s2 = red[4] + red[5] + red[6] + red[7];
  const float mu = s * (1.f / E_);
  const float inv = rsqrtf(s2 * (1.f / E_) - mu * mu + 1e-5f);
  const float4 w4 = ((const float4*)gw)[tid];
  const float4 b4 = ((const float4*)gb)[tid];
  const int e0 = tid * 4;
  f16x4 o;
  o[0] = (f16)((v.x - mu) * inv * w4.x + b4.x);
  o[1] = (f16)((v.y - mu) * inv * w4.y + b4.y);
  o[2] = (f16)((v.z - mu) * inv * w4.z + b4.z);
  o[3] = (f16)((v.w - mu) * inv * w4.w + b4.w);
  const int b = row >> 11, t = row & (T_ - 1);
  const size_t off2 = ((size_t)(b * H_ + (e0 >> 6)) * T_ + t) * HD_ + (e0 & 63);
  *(f16x4*)(outp + off2) = o;
}

// ---------------- flash attention: causal, scores*2/sqrt(64) = *0.25 -------
__global__ __launch_bounds__(256) void k_attn(const f16* __restrict__ Q,
                                              const f16* __restrict__ K,
                                              const f16* __restrict__ V,
                                              f16* __restrict__ AO) {
  __shared__ __align__(16) f16 Kt[64][72];
  __shared__ __align__(16) f16 Vt[64][72];
  __shared__ __align__(16) f16 Ps[4][16][72];
  const int qi = blockIdx.x, bh = blockIdx.y;
  const int b = bh >> 4, h = bh & 15;
  const int tid = threadIdx.x, wid = tid >> 6, lane = tid & 63;
  const int lg = lane >> 4, lc = lane & 15;
  const size_t hbase = (size_t)bh * T_ * HD_;
  const int qb = qi * 64;
  f16x8 qf[2];
  {
    const int qrow = qb + wid * 16 + lc;
#pragma unroll
    for (int ks = 0; ks < 2; ++ks)
      qf[ks] = *(const f16x8*)(Q + hbase + (size_t)qrow * HD_ + ks * 32 + lg * 8);
  }
  f32x4 o[4] = {};
  float m_run[4] = {-1e30f, -1e30f, -1e30f, -1e30f};
  float l_run[4] = {};
  const int qrow_d = qb + wid * 16 + lg * 4;
  for (int kt = 0; kt <= qi; ++kt) {
    {
      const int r = tid >> 2, cs = (tid & 3) * 16;
      const f16* ksrc = K + hbase + (size_t)(kt * 64 + r) * HD_ + cs;
      *(f16x8*)&Kt[r][cs] = *(const f16x8*)ksrc;
      *(f16x8*)&Kt[r][cs + 8] = *(const f16x8*)(ksrc + 8);
      const f16* vsrc = V + hbase + (size_t)(kt * 64 + lane) * HD_ + wid * 16;
      f16x8 va = *(const f16x8*)vsrc;
      f16x8 vb = *(const f16x8*)(vsrc + 8);
#pragma unroll
      for (int u = 0; u < 8; ++u) {
        Vt[wid * 16 + u][lane] = va[u];
        Vt[wid * 16 + 8 + u][lane] = vb[u];
      }
    }
    __syncthreads();
    f32x4 s[4] = {};
#pragma unroll
    for (int nt = 0; nt < 4; ++nt)
#pragma unroll
      for (int ks = 0; ks < 2; ++ks) {
        f16x8 kf = *(const f16x8*)&Kt[nt * 16 + lc][ks * 32 + lg * 8];
        s[nt] = mfma16(qf[ks], kf, s[nt]);
      }
    const bool diag = (kt == qi);
#pragma unroll
    for (int nt = 0; nt < 4; ++nt) {
      const int colg = kt * 64 + nt * 16 + lc;
#pragma unroll
      for (int r = 0; r < 4; ++r) {
        float v = s[nt][r] * 0.25f;
        if (diag && colg > qrow_d + r) v = -1e30f;
        s[nt][r] = v;
      }
    }
    float scalev[4];
#pragma unroll
    for (int r = 0; r < 4; ++r) {
      float m = fmaxf(fmaxf(s[0][r], s[1][r]), fmaxf(s[2][r], s[3][r]));
#pragma unroll
      for (int of = 1; of < 16; of <<= 1) m = fmaxf(m, __shfl_xor(m, of));
      const float mn = fmaxf(m_run[r], m);
      scalev[r] = __expf(m_run[r] - mn);
      m_run[r] = mn;
    }
    float ladd[4] = {};
#pragma unroll
    for (int nt = 0; nt < 4; ++nt)
#pragma unroll
      for (int r = 0; r < 4; ++r) {
        const float p = __expf(s[nt][r] - m_run[r]);
        s[nt][r] = p;
        ladd[r] += p;
      }
#pragma unroll
    for (int r = 0; r < 4; ++r) {
      float la = ladd[r];
#pragma unroll
      for (int of = 1; of < 16; of <<= 1) la += __shfl_xor(la, of);
      l_run[r] = l_run[r] * scalev[r] + la;
      o[0][r] *= scalev[r];
      o[1][r] *= scalev[r];
      o[2][r] *= scalev[r];
      o[3][r] *= scalev[r];
    }
#pragma unroll
    for (int nt = 0; nt < 4; ++nt)
#pragma unroll
      for (int r = 0; r < 4; ++r)
        Ps[wid][lg * 4 + r][nt * 16 + lc] = (f16)s[nt][r];
    f16x8 pf[2];
#pragma unroll
    for (int ks = 0; ks < 2; ++ks)
      pf[ks] = *(const f16x8*)&Ps[wid][lc][ks * 32 + lg * 8];
#pragma unroll
    for (int nt = 0; nt < 4; ++nt)
#pragma unroll
      for (int ks = 0; ks < 2; ++ks) {
        f16x8 vf = *(const f16x8*)&Vt[nt * 16 + lc][ks * 32 + lg * 8];
        o[nt] = mfma16(pf[ks], vf, o[nt]);
      }
    __syncthreads();
  }
#pragma unroll
  for (int nt = 0; nt < 4; ++nt)
#pragma unroll
    for (int r = 0; r < 4; ++r) {
      const float val = o[nt][r] / l_run[r];
      const int qrow = qrow_d + r;
      AO[((size_t)(b * T_ + qrow)) * E_ + h * HD_ + nt * 16 + lc] = (f16)val;
    }
}

// ---------------- out GEMM: C = A @ WO^T + bias -----------------------------
__global__ __launch_bounds__(256) void k_gemm_out(
    const f16* __restrict__ A, const f16* __restrict__ W,
    const float* __restrict__ bias, float* __restrict__ C) {
  __shared__ __align__(16) f16 As[128][72];
  __shared__ __align__(16) f16 Bs[128][72];
  const int m0 = blockIdx.x * 128, n0 = blockIdx.y * 128;
  const int tid = threadIdx.x;
  const int wid = tid >> 6, lane = tid & 63;
  const int wr = wid >> 1, wc = wid & 1;
  const int lg = lane >> 4, lc = lane & 15;
  f32x4 acc[4][4] = {};
  for (int kt = 0; kt < E_; kt += 64) {
#pragma unroll
    for (int it = 0; it < 4; ++it) {
      const int r = it * 32 + (tid >> 3);
      const int cs = (tid & 7) * 8;
      *(f16x8*)&As[r][cs] = *(const f16x8*)(A + (size_t)(m0 + r) * E_ + kt + cs);
      *(f16x8*)&Bs[r][cs] = *(const f16x8*)(W + (size_t)(n0 + r) * E_ + kt + cs);
    }
    __syncthreads();
    f16x8 af[4][2], bf[4][2];
#pragma unroll
    for (int mi = 0; mi < 4; ++mi)
#pragma unroll
      for (int ks = 0; ks < 2; ++ks) {
        af[mi][ks] = *(const f16x8*)&As[wr * 64 + mi * 16 + lc][ks * 32 + lg * 8];
        bf[mi][ks] = *(const f16x8*)&Bs[wc * 64 + mi * 16 + lc][ks * 32 + lg * 8];
      }
#pragma unroll
    for (int mi = 0; mi < 4; ++mi)
#pragma unroll
      for (int ni = 0; ni < 4; ++ni)
#pragma unroll
        for (int ks = 0; ks < 2; ++ks)
          acc[mi][ni] = mfma16(af[mi][ks], bf[ni][ks], acc[mi][ni]);
    __syncthreads();
  }
#pragma unroll
  for (int mi = 0; mi < 4; ++mi) {
    const int r0 = m0 + wr * 64 + mi * 16 + lg * 4;
#pragma unroll
    for (int ni = 0; ni < 4; ++ni) {
      const int col = n0 + wc * 64 + ni * 16 + lc;
      const float bv = bias[col];
#pragma unroll
      for (int q = 0; q < 4; ++q)
        C[(size_t)(r0 + q) * E_ + col] = acc[mi][ni][q] + bv;
    }
  }
}

}  // namespace

extern "C" void kernel_launch(void* const* d_in, const int* in_sizes, int n_in,
                              void* d_out, int out_size, void* d_ws, size_t ws_size,
                              hipStream_t stream) {
  (void)in_sizes; (void)n_in; (void)out_size; (void)ws_size;
  const float* x      = (const float*)d_in[0];
  const int*   tok    = (const int*)d_in[1];
  const float* q_wih  = (const float*)d_in[2];
  const float* q_whh  = (const float*)d_in[3];
  const float* q_lin  = (const float*)d_in[4];
  const float* k_wih  = (const float*)d_in[5];
  const float* k_whh  = (const float*)d_in[6];
  const float* k_lin  = (const float*)d_in[7];
  const float* v_emb  = (const float*)d_in[8];
  const float* q_ln_w = (const float*)d_in[9];
  const float* q_ln_b = (const float*)d_in[10];
  const float* k_ln_w = (const float*)d_in[11];
  const float* k_ln_b = (const float*)d_in[12];
  const float* out_w  = (const float*)d_in[13];
  const float* out_b  = (const float*)d_in[14];
  float* outp = (float*)d_out;

  char* ws = (char*)d_ws;
  size_t off = 0;
  auto take = [&](size_t bytes) -> void* {
    void* p = ws + off;
    off += (bytes + 255) & ~(size_t)255;
    return p;
  };
  f16* WO   = (f16*)take((size_t)E_ * E_ * 2);
  f16* AQ   = (f16*)take((size_t)M_ * E_ * 2);
  f16* AK   = (f16*)take((size_t)M_ * E_ * 2);
  f16* VH   = (f16*)take((size_t)M_ * E_ * 2);
  f16* QH   = (f16*)take((size_t)M_ * E_ * 2);
  f16* KH   = (f16*)take((size_t)M_ * E_ * 2);
  f16* AO   = (f16*)take((size_t)M_ * E_ * 2);
  float* XWQ  = (float*)take((size_t)M_ * G3_ * 4);
  float* XWK  = (float*)take((size_t)M_ * G3_ * 4);
  float* QPRE = (float*)take((size_t)M_ * E_ * 4);
  float* KPRE = (float*)take((size_t)M_ * E_ * 4);

  k_prep<<<dim3(M_), dim3(256), 0, stream>>>(x, tok, q_wih, k_wih, v_emb, VH, AQ, AK, XWQ, XWK);

  k_mega<<<dim3(521), dim3(256), 0, stream>>>(XWQ, XWK, q_whh, k_whh, AQ, AK,
                                              q_lin, k_lin, x, QPRE, KPRE, out_w, WO);

  k_fix<<<dim3(M_ / 128, E_ / 128, 2), dim3(256), 0, stream>>>(AQ, AK, q_lin, k_lin, QPRE, KPRE);
  k_ln<<<dim3(M_, 2), dim3(256), 0, stream>>>(QPRE, KPRE, q_ln_w, q_ln_b, k_ln_w, k_ln_b, QH, KH);

  k_attn<<<dim3(T_ / 64, B_ * H_), dim3(256), 0, stream>>>(QH, KH, VH, AO);
  k_gemm_out<<<dim3(M_ / 128, E_ / 128), dim3(256), 0, stream>>>(AO, WO, out_b, outp);
}

// Round 11
// 934.630 us; speedup vs baseline: 1.5008x; 1.0063x over previous
//
#include <hip/hip_runtime.h>

// R11: GRU MACs switched v_dot2_f32_f16 -> v_pk_fma_f16. Fitting R2/R6-R10:
// per-step cost ~96 dots x 8cy regardless of dependency structure => dot2 is
// quarter-rate on gfx950; packed f16 fma is the full-rate path (f16 peak = 2x
// f32). f16x2 accumulators (2/gate, 16-term partials, ~1e-3 pre-act err),
// f32 final combine. Single-variable change vs R10; all else identical.

namespace {

constexpr int B_ = 2, T_ = 2048, E_ = 1024, H_ = 16, HD_ = 64, G3_ = 192, M_ = B_ * T_;
constexpr float SRg = -1.4426950408889634f;  // -log2(e), r/z gates
constexpr float SNg = 2.8853900817779268f;   // 2*log2(e), n gate

typedef _Float16 f16;
typedef _Float16 f16x8 __attribute__((ext_vector_type(8)));
typedef _Float16 f16x4 __attribute__((ext_vector_type(4)));
typedef _Float16 f16x2 __attribute__((ext_vector_type(2)));
typedef float f32x4 __attribute__((ext_vector_type(4)));

__device__ __forceinline__ f32x4 mfma16(f16x8 a, f16x8 b, f32x4 c) {
  return __builtin_amdgcn_mfma_f32_16x16x32_f16(a, b, c, 0, 0, 0);
}

// packed f16 fma: a*b+c elementwise -> v_pk_fma_f16
__device__ __forceinline__ f16x2 pkfma(f16x2 a, f16x2 b, f16x2 c) {
#if __has_builtin(__builtin_elementwise_fma)
  return __builtin_elementwise_fma(a, b, c);
#else
  return a * b + c;  // -ffp-contract=fast fuses to v_pk_fma_f16
#endif
}

__device__ __forceinline__ float exp2_(float x) {
#if __has_builtin(__builtin_amdgcn_exp2f)
  return __builtin_amdgcn_exp2f(x);
#else
  return exp2f(x);
#endif
}
__device__ __forceinline__ float rcp_(float x) {
#if __has_builtin(__builtin_amdgcn_rcpf)
  return __builtin_amdgcn_rcpf(x);
#else
  return 1.f / x;
#endif
}

// stage a 128x64 f32 tile -> f16 LDS [128][72]; same thread mapping as f16 path
__device__ __forceinline__ void stage_w_f32(const float* __restrict__ Wf,
                                            f16 (*Bs)[72], int n0, int kt,
                                            int tid) {
#pragma unroll
  for (int it = 0; it < 4; ++it) {
    const int r = it * 32 + (tid >> 3);
    const int cs = (tid & 7) * 8;
    const float* src = Wf + (size_t)(n0 + r) * E_ + kt + cs;
    float4 w0 = *(const float4*)src;
    float4 w1 = *(const float4*)(src + 4);
    f16x8 o = {(f16)w0.x, (f16)w0.y, (f16)w0.z, (f16)w0.w,
               (f16)w1.x, (f16)w1.y, (f16)w1.z, (f16)w1.w};
    *(f16x8*)&Bs[r][cs] = o;
  }
}

// ---------------- prep: v = silu(x)*emb, x_proj pooling, xw = pool16(x)@wih^T
__global__ __launch_bounds__(256) void k_prep(
    const float* __restrict__ x, const int* __restrict__ tok,
    const float* __restrict__ wihq, const float* __restrict__ wihk,
    const float* __restrict__ v_emb,
    f16* __restrict__ vh, f16* __restrict__ aq, f16* __restrict__ ak,
    float* __restrict__ xwq, float* __restrict__ xwk) {
  __shared__ float xs[E_];
  __shared__ float xp[64];
  const int row = blockIdx.x;
  const int b = row >> 11, t = row & (T_ - 1);
  const int tid = threadIdx.x;
  const float* xrow = x + (size_t)row * E_;
  {
    const int tk = tok[row];
    float4 xv = ((const float4*)xrow)[tid];
    ((float4*)xs)[tid] = xv;
    float4 ev = ((const float4*)(v_emb + (size_t)tk * E_))[tid];
    f16x4 o;
    o[0] = (f16)(xv.x / (1.f + __expf(-xv.x)) * ev.x);
    o[1] = (f16)(xv.y / (1.f + __expf(-xv.y)) * ev.y);
    o[2] = (f16)(xv.z / (1.f + __expf(-xv.z)) * ev.z);
    o[3] = (f16)(xv.w / (1.f + __expf(-xv.w)) * ev.w);
    const int e0 = tid * 4;
    const size_t voff = ((size_t)(b * H_ + (e0 >> 6)) * T_ + t) * HD_ + (e0 & 63);
    *(f16x4*)(vh + voff) = o;
  }
  __syncthreads();
  if (tid < 64) {
    float s = 0.f;
#pragma unroll
    for (int j = 0; j < 16; ++j) s += xs[tid * 16 + j];
    xp[tid] = s * (1.f / 16.f);
  }
  for (int i = tid; i < 960; i += 256) {
    int s0 = (i * 1024) / 960;
    int e0 = ((i + 1) * 1024 + 959) / 960;
    float m = xs[s0];
    if (e0 - s0 == 2) m = (m + xs[s0 + 1]) * 0.5f;
    f16 hv = (f16)m;
    aq[(size_t)row * E_ + 64 + i] = hv;
    ak[(size_t)row * E_ + 64 + i] = hv;
  }
  __syncthreads();
  for (int o = tid; o < 2 * G3_; o += 256) {
    const int chain = o / G3_, g = o % G3_;
    const float* wrow = (chain ? wihk : wihq) + (size_t)g * 64;
    float acc = 0.f;
#pragma unroll
    for (int c = 0; c < 16; ++c) {
      float4 wv = *(const float4*)(wrow + c * 4);
      acc += xp[c * 4] * wv.x + xp[c * 4 + 1] * wv.y +
             xp[c * 4 + 2] * wv.z + xp[c * 4 + 3] * wv.w;
    }
    const float sc = (g < 128) ? SRg : SNg;
    (chain ? xwk : xwq)[(size_t)row * G3_ + g] = acc * sc;
  }
}

// ---------------- GRU core: one wave, lane j owns h_j -----------------------
// MACs via v_pk_fma_f16 (full-rate packed f16), 2 f16x2 accs per gate,
// f32 final combine. Otherwise identical to R10/R7.
__device__ __forceinline__ void gru_core(const float* __restrict__ xw,
                                         const float* __restrict__ whh,
                                         f16* __restrict__ a, int lane) {
  __builtin_amdgcn_s_setprio(3);
  f16x2 wr[32], wz[32], wn[32];
#pragma unroll
  for (int i = 0; i < 32; ++i) {
    wr[i] = {(f16)(whh[(size_t)lane * 64 + i] * SRg),
             (f16)(whh[(size_t)lane * 64 + i + 32] * SRg)};
    wz[i] = {(f16)(whh[(size_t)(64 + lane) * 64 + i] * SRg),
             (f16)(whh[(size_t)(64 + lane) * 64 + i + 32] * SRg)};
    wn[i] = {(f16)(whh[(size_t)(128 + lane) * 64 + i] * SNg),
             (f16)(whh[(size_t)(128 + lane) * 64 + i + 32] * SNg)};
  }
  float h = 0.f;
  float xr = xw[lane], xz = xw[64 + lane], xn = xw[128 + lane];
  f16* ap = a + lane;
  for (int t = 0; t < T_; ++t) {
    // pack pair (h_l, h_{l+32}) via permlane32_swap (VALU, no LDS)
    const unsigned hu = (unsigned)__builtin_bit_cast(unsigned short, (f16)h);
    int va = (int)hu, vb = (int)hu;
    asm volatile("v_permlane32_swap_b32 %0, %1" : "+v"(va), "+v"(vb));
    const int pk = (int)(hu | ((unsigned)va << 16));
    // prefetch next step's xw — consumed after the dots
    const int tn = (t + 1 < T_) ? t + 1 : t;
    const float* nx = xw + (size_t)tn * G3_;
    const float nxr = nx[lane], nxz = nx[64 + lane], nxn = nx[128 + lane];
    // broadcast: 32 readlanes batched
    int hp[32];
#pragma unroll
    for (int i = 0; i < 32; ++i) hp[i] = __builtin_amdgcn_readlane(pk, i);
    // gate MACs: v_pk_fma_f16, 2 accumulators per gate (16 products each)
    f16x2 r0 = {0.f16, 0.f16}, r1 = r0, n0 = r0, n1 = r0, z0 = r0, z1 = r0;
#pragma unroll
    for (int i = 0; i < 16; ++i) {
      const f16x2 h0 = __builtin_bit_cast(f16x2, hp[2 * i]);
      const f16x2 h1 = __builtin_bit_cast(f16x2, hp[2 * i + 1]);
      r0 = pkfma(wr[2 * i], h0, r0);
      r1 = pkfma(wr[2 * i + 1], h1, r1);
      n0 = pkfma(wn[2 * i], h0, n0);
      n1 = pkfma(wn[2 * i + 1], h1, n1);
      z0 = pkfma(wz[2 * i], h0, z0);
      z1 = pkfma(wz[2 * i + 1], h1, z1);
    }
    const float ar = xr + ((float)r0[0] + (float)r0[1]) + ((float)r1[0] + (float)r1[1]);
    const float an = ((float)n0[0] + (float)n0[1]) + ((float)n1[0] + (float)n1[1]);
    const float az = xz + ((float)z0[0] + (float)z0[1]) + ((float)z1[0] + (float)z1[1]);
    const float r = rcp_(1.f + exp2_(ar));
    const float p2 = fmaf(r, an, xn);
    const float n = fmaf(-2.f, rcp_(1.f + exp2_(p2)), 1.f);  // tanh
    const float z = rcp_(1.f + exp2_(az));
    h = fmaf(z, h - n, n);
    ap[(size_t)t * E_] = (f16)h;
    xr = nxr; xz = nxz; xn = nxn;
  }
}

// ---------------- megakernel: GRU (block 0) + QK partial GEMMs (+x) + WO cvt
__global__ __launch_bounds__(256, 1) void k_mega(
    const float* __restrict__ xwq, const float* __restrict__ xwk,
    const float* __restrict__ whhq, const float* __restrict__ whhk,
    f16* __restrict__ aq, f16* __restrict__ ak,
    const float* __restrict__ WQf, const float* __restrict__ WKf,
    const float* __restrict__ x,
    float* __restrict__ QPRE, float* __restrict__ KPRE,
    const float* __restrict__ out_w, f16* __restrict__ WO) {
  __shared__ __align__(16) f16 As[128][72];
  __shared__ __align__(16) f16 Bs[128][72];
  const int bx = blockIdx.x;
  const int tid = threadIdx.x;
  if (bx == 0) {
    const int wid = tid >> 6, lane = tid & 63;
    const int qk = wid >> 1, b = wid & 1;
    const float* xw = (qk ? xwk : xwq) + (size_t)b * T_ * G3_;
    const float* whh = qk ? whhk : whhq;
    f16* a = (qk ? ak : aq) + (size_t)b * T_ * E_;
    gru_core(xw, whh, a, lane);
    return;
  }
  if (bx <= 512) {
    const int bid = bx - 1;
    const int chain = bid >> 8, tile = bid & 255;
    const int m0 = (tile >> 3) * 128, n0 = (tile & 7) * 128;
    const f16* A = chain ? ak : aq;
    const float* Wf = chain ? WKf : WQf;
    float* C = chain ? KPRE : QPRE;
    const int wid = tid >> 6, lane = tid & 63;
    const int wr = wid >> 1, wc = wid & 1;
    const int lg = lane >> 4, lc = lane & 15;
    f32x4 acc[4][4] = {};
    for (int kt = 64; kt < E_; kt += 64) {
#pragma unroll
      for (int it = 0; it < 4; ++it) {
        const int r = it * 32 + (tid >> 3);
        const int cs = (tid & 7) * 8;
        *(f16x8*)&As[r][cs] = *(const f16x8*)(A + (size_t)(m0 + r) * E_ + kt + cs);
      }
      stage_w_f32(Wf, Bs, n0, kt, tid);
      __syncthreads();
      f16x8 af[4][2], bf[4][2];
#pragma unroll
      for (int mi = 0; mi < 4; ++mi)
#pragma unroll
        for (int ks = 0; ks < 2; ++ks) {
          af[mi][ks] = *(const f16x8*)&As[wr * 64 + mi * 16 + lc][ks * 32 + lg * 8];
          bf[mi][ks] = *(const f16x8*)&Bs[wc * 64 + mi * 16 + lc][ks * 32 + lg * 8];
        }
#pragma unroll
      for (int mi = 0; mi < 4; ++mi)
#pragma unroll
        for (int ni = 0; ni < 4; ++ni)
#pragma unroll
          for (int ks = 0; ks < 2; ++ks)
            acc[mi][ni] = mfma16(af[mi][ks], bf[ni][ks], acc[mi][ni]);
      __syncthreads();
    }
#pragma unroll
    for (int mi = 0; mi < 4; ++mi) {
      const int r0 = m0 + wr * 64 + mi * 16 + lg * 4;
#pragma unroll
      for (int ni = 0; ni < 4; ++ni) {
        const int col = n0 + wc * 64 + ni * 16 + lc;
#pragma unroll
        for (int q = 0; q < 4; ++q) {
          const size_t idx = (size_t)(r0 + q) * E_ + col;
          C[idx] = acc[mi][ni][q] + x[idx];
        }
      }
    }
    return;
  }
  {
    const int cb = bx - 513;
    for (int i = cb * 256 + tid; i < E_ * E_ / 4; i += 8 * 256) {
      float4 v = ((const float4*)out_w)[i];
      f16x4 o = {(f16)v.x, (f16)v.y, (f16)v.z, (f16)v.w};
      *(f16x4*)(WO + (size_t)i * 4) = o;
    }
  }
}

// ---------------- fix: C += A[:,0:64] @ W[:,0:64]^T -------------------------
__global__ __launch_bounds__(256) void k_fix(
    const f16* __restrict__ aq, const f16* __restrict__ ak,
    const float* __restrict__ WQf, const float* __restrict__ WKf,
    float* __restrict__ QPRE, float* __restrict__ KPRE) {
  __shared__ __align__(16) f16 As[128][72];
  __shared__ __align__(16) f16 Bs[128][72];
  const int chain = blockIdx.z;
  const f16* A = chain ? ak : aq;
  const float* Wf = chain ? WKf : WQf;
  float* C = chain ? KPRE : QPRE;
  const int m0 = blockIdx.x * 128, n0 = blockIdx.y * 128;
  const int tid = threadIdx.x;
  const int wid = tid >> 6, lane = tid & 63;
  const int wr = wid >> 1, wc = wid & 1;
  const int lg = lane >> 4, lc = lane & 15;
#pragma unroll
  for (int it = 0; it < 4; ++it) {
    const int r = it * 32 + (tid >> 3);
    const int cs = (tid & 7) * 8;
    *(f16x8*)&As[r][cs] = *(const f16x8*)(A + (size_t)(m0 + r) * E_ + cs);
  }
  stage_w_f32(Wf, Bs, n0, 0, tid);
  __syncthreads();
  f32x4 acc[4][4] = {};
  f16x8 af[4][2], bf[4][2];
#pragma unroll
  for (int mi = 0; mi < 4; ++mi)
#pragma unroll
    for (int ks = 0; ks < 2; ++ks) {
      af[mi][ks] = *(const f16x8*)&As[wr * 64 + mi * 16 + lc][ks * 32 + lg * 8];
      bf[mi][ks] = *(const f16x8*)&Bs[wc * 64 + mi * 16 + lc][ks * 32 + lg * 8];
    }
#pragma unroll
  for (int mi = 0; mi < 4; ++mi)
#pragma unroll
    for (int ni = 0; ni < 4; ++ni)
#pragma unroll
      for (int ks = 0; ks < 2; ++ks)
        acc[mi][ni] = mfma16(af[mi][ks], bf[ni][ks], acc[mi][ni]);
#pragma unroll
  for (int mi = 0; mi < 4; ++mi) {
    const int r0 = m0 + wr * 64 + mi * 16 + lg * 4;
#pragma unroll
    for (int ni = 0; ni < 4; ++ni) {
      const int col = n0 + wc * 64 + ni * 16 + lc;
#pragma unroll
      for (int q = 0; q < 4; ++q) {
        const size_t idx = (size_t)(r0 + q) * E_ + col;
        C[idx] += acc[mi][ni][q];
      }
    }
  }
}

// ---------------- LayerNorm (both chains), write f16 in [B,H,T,HD] ---------
__global__ __launch_bounds__(256) void k_ln(
    const float* __restrict__ qpre, const float* __restrict__ kpre,
    const float* __restrict__ qw, const float* __restrict__ qb,
    const float* __restrict__ kw, const float* __restrict__ kb,
    f16* __restrict__ qh, f16* __restrict__ kh) {
  const int chain = blockIdx.y;
  const float* pre = chain ? kpre : qpre;
  const float* gw = chain ? kw : qw;
  const float* gb = chain ? kb : qb;
  f16* outp = chain ? kh : qh;
  const int row = blockIdx.x;
  const int tid = threadIdx.x;
  const float4 v = ((const float4*)(pre + (size_t)row * E_))[tid];
  float s = v.x + v.y + v.z + v.w;
  float s2 = v.x * v.x + v.y * v.y + v.z * v.z + v.w * v.w;
#pragma unroll
  for (int off = 32; off; off >>= 1) {
    s += __shfl_xor(s, off);
    s2 += __shfl_xor(s2, off);
  }
  __shared__ float red[8];
  const int wid = tid >> 6, lane = tid & 63;
  if (!lane) { red[wid] = s; red[4 + wid] = s2; }
  __syncthreads();
  s = red[0] + red[1] + red[2] + red[3];
  s2 = red[4] + red[5] + red[6] + red[7];
  const float mu = s * (1.f / E_);
  const float inv = rsqrtf(s2 * (1.f / E_) - mu * mu + 1e-5f);
  const float4 w4 = ((const float4*)gw)[tid];
  const float4 b4 = ((const float4*)gb)[tid];
  const int e0 = tid * 4;
  f16x4 o;
  o[0] = (f16)((v.x - mu) * inv * w4.x + b4.x);
  o[1] = (f16)((v.y - mu) * inv * w4.y + b4.y);
  o[2] = (f16)((v.z - mu) * inv * w4.z + b4.z);
  o[3] = (f16)((v.w - mu) * inv * w4.w + b4.w);
  const int b = row >> 11, t = row & (T_ - 1);
  const size_t off2 = ((size_t)(b * H_ + (e0 >> 6)) * T_ + t) * HD_ + (e0 & 63);
  *(f16x4*)(outp + off2) = o;
}

// ---------------- flash attention: causal, scores*2/sqrt(64) = *0.25 -------
__global__ __launch_bounds__(256) void k_attn(const f16* __restrict__ Q,
                                              const f16* __restrict__ K,
                                              const f16* __restrict__ V,
                                              f16* __restrict__ AO) {
  __shared__ __align__(16) f16 Kt[64][72];
  __shared__ __align__(16) f16 Vt[64][72];
  __shared__ __align__(16) f16 Ps[4][16][72];
  const int qi = blockIdx.x, bh = blockIdx.y;
  const int b = bh >> 4, h = bh & 15;
  const int tid = threadIdx.x, wid = tid >> 6, lane = tid & 63;
  const int lg = lane >> 4, lc = lane & 15;
  const size_t hbase = (size_t)bh * T_ * HD_;
  const int qb = qi * 64;
  f16x8 qf[2];
  {
    const int qrow = qb + wid * 16 + lc;
#pragma unroll
    for (int ks = 0; ks < 2; ++ks)
      qf[ks] = *(const f16x8*)(Q + hbase + (size_t)qrow * HD_ + ks * 32 + lg * 8);
  }
  f32x4 o[4] = {};
  float m_run[4] = {-1e30f, -1e30f, -1e30f, -1e30f};
  float l_run[4] = {};
  const int qrow_d = qb + wid * 16 + lg * 4;
  for (int kt = 0; kt <= qi; ++kt) {
    {
      const int r = tid >> 2, cs = (tid & 3) * 16;
      const f16* ksrc = K + hbase + (size_t)(kt * 64 + r) * HD_ + cs;
      *(f16x8*)&Kt[r][cs] = *(const f16x8*)ksrc;
      *(f16x8*)&Kt[r][cs + 8] = *(const f16x8*)(ksrc + 8);
      const f16* vsrc = V + hbase + (size_t)(kt * 64 + lane) * HD_ + wid * 16;
      f16x8 va = *(const f16x8*)vsrc;
      f16x8 vb = *(const f16x8*)(vsrc + 8);
#pragma unroll
      for (int u = 0; u < 8; ++u) {
        Vt[wid * 16 + u][lane] = va[u];
        Vt[wid * 16 + 8 + u][lane] = vb[u];
      }
    }
    __syncthreads();
    f32x4 s[4] = {};
#pragma unroll
    for (int nt = 0; nt < 4; ++nt)
#pragma unroll
      for (int ks = 0; ks < 2; ++ks) {
        f16x8 kf = *(const f16x8*)&Kt[nt * 16 + lc][ks * 32 + lg * 8];
        s[nt] = mfma16(qf[ks], kf, s[nt]);
      }
    const bool diag = (kt == qi);
#pragma unroll
    for (int nt = 0; nt < 4; ++nt) {
      const int colg = kt * 64 + nt * 16 + lc;
#pragma unroll
      for (int r = 0; r < 4; ++r) {
        float v = s[nt][r] * 0.25f;
        if (diag && colg > qrow_d + r) v = -1e30f;
        s[nt][r] = v;
      }
    }
    float scalev[4];
#pragma unroll
    for (int r = 0; r < 4; ++r) {
      float m = fmaxf(fmaxf(s[0][r], s[1][r]), fmaxf(s[2][r], s[3][r]));
#pragma unroll
      for (int of = 1; of < 16; of <<= 1) m = fmaxf(m, __shfl_xor(m, of));
      const float mn = fmaxf(m_run[r], m);
      scalev[r] = __expf(m_run[r] - mn);
      m_run[r] = mn;
    }
    float ladd[4] = {};
#pragma unroll
    for (int nt = 0; nt < 4; ++nt)
#pragma unroll
      for (int r = 0; r < 4; ++r) {
        const float p = __expf(s[nt][r] - m_run[r]);
        s[nt][r] = p;
        ladd[r] += p;
      }
#pragma unroll
    for (int r = 0; r < 4; ++r) {
      float la = ladd[r];
#pragma unroll
      for (int of = 1; of < 16; of <<= 1) la += __shfl_xor(la, of);
      l_run[r] = l_run[r] * scalev[r] + la;
      o[0][r] *= scalev[r];
      o[1][r] *= scalev[r];
      o[2][r] *= scalev[r];
      o[3][r] *= scalev[r];
    }
#pragma unroll
    for (int nt = 0; nt < 4; ++nt)
#pragma unroll
      for (int r = 0; r < 4; ++r)
        Ps[wid][lg * 4 + r][nt * 16 + lc] = (f16)s[nt][r];
    f16x8 pf[2];
#pragma unroll
    for (int ks = 0; ks < 2; ++ks)
      pf[ks] = *(const f16x8*)&Ps[wid][lc][ks * 32 + lg * 8];
#pragma unroll
    for (int nt = 0; nt < 4; ++nt)
#pragma unroll
      for (int ks = 0; ks < 2; ++ks) {
        f16x8 vf = *(const f16x8*)&Vt[nt * 16 + lc][ks * 32 + lg * 8];
        o[nt] = mfma16(pf[ks], vf, o[nt]);
      }
    __syncthreads();
  }
#pragma unroll
  for (int nt = 0; nt < 4; ++nt)
#pragma unroll
    for (int r = 0; r < 4; ++r) {
      const float val = o[nt][r] / l_run[r];
      const int qrow = qrow_d + r;
      AO[((size_t)(b * T_ + qrow)) * E_ + h * HD_ + nt * 16 + lc] = (f16)val;
    }
}

// ---------------- out GEMM: C = A @ WO^T + bias -----------------------------
__global__ __launch_bounds__(256) void k_gemm_out(
    const f16* __restrict__ A, const f16* __restrict__ W,
    const float* __restrict__ bias, float* __restrict__ C) {
  __shared__ __align__(16) f16 As[128][72];
  __shared__ __align__(16) f16 Bs[128][72];
  const int m0 = blockIdx.x * 128, n0 = blockIdx.y * 128;
  const int tid = threadIdx.x;
  const int wid = tid >> 6, lane = tid & 63;
  const int wr = wid >> 1, wc = wid & 1;
  const int lg = lane >> 4, lc = lane & 15;
  f32x4 acc[4][4] = {};
  for (int kt = 0; kt < E_; kt += 64) {
#pragma unroll
    for (int it = 0; it < 4; ++it) {
      const int r = it * 32 + (tid >> 3);
      const int cs = (tid & 7) * 8;
      *(f16x8*)&As[r][cs] = *(const f16x8*)(A + (size_t)(m0 + r) * E_ + kt + cs);
      *(f16x8*)&Bs[r][cs] = *(const f16x8*)(W + (size_t)(n0 + r) * E_ + kt + cs);
    }
    __syncthreads();
    f16x8 af[4][2], bf[4][2];
#pragma unroll
    for (int mi = 0; mi < 4; ++mi)
#pragma unroll
      for (int ks = 0; ks < 2; ++ks) {
        af[mi][ks] = *(const f16x8*)&As[wr * 64 + mi * 16 + lc][ks * 32 + lg * 8];
        bf[mi][ks] = *(const f16x8*)&Bs[wc * 64 + mi * 16 + lc][ks * 32 + lg * 8];
      }
#pragma unroll
    for (int mi = 0; mi < 4; ++mi)
#pragma unroll
      for (int ni = 0; ni < 4; ++ni)
#pragma unroll
        for (int ks = 0; ks < 2; ++ks)
          acc[mi][ni] = mfma16(af[mi][ks], bf[ni][ks], acc[mi][ni]);
    __syncthreads();
  }
#pragma unroll
  for (int mi = 0; mi < 4; ++mi) {
    const int r0 = m0 + wr * 64 + mi * 16 + lg * 4;
#pragma unroll
    for (int ni = 0; ni < 4; ++ni) {
      const int col = n0 + wc * 64 + ni * 16 + lc;
      const float bv = bias[col];
#pragma unroll
      for (int q = 0; q < 4; ++q)
        C[(size_t)(r0 + q) * E_ + col] = acc[mi][ni][q] + bv;
    }
  }
}

}  // namespace

extern "C" void kernel_launch(void* const* d_in, const int* in_sizes, int n_in,
                              void* d_out, int out_size, void* d_ws, size_t ws_size,
                              hipStream_t stream) {
  (void)in_sizes; (void)n_in; (void)out_size; (void)ws_size;
  const float* x      = (const float*)d_in[0];
  const int*   tok    = (const int*)d_in[1];
  const float* q_wih  = (const float*)d_in[2];
  const float* q_whh  = (const float*)d_in[3];
  const float* q_lin  = (const float*)d_in[4];
  const float* k_wih  = (const float*)d_in[5];
  const float* k_whh  = (const float*)d_in[6];
  const float* k_lin  = (const float*)d_in[7];
  const float* v_emb  = (const float*)d_in[8];
  const float* q_ln_w = (const float*)d_in[9];
  const float* q_ln_b = (const float*)d_in[10];
  const float* k_ln_w = (const float*)d_in[11];
  const float* k_ln_b = (const float*)d_in[12];
  const float* out_w  = (const float*)d_in[13];
  const float* out_b  = (const float*)d_in[14];
  float* outp = (float*)d_out;

  char* ws = (char*)d_ws;
  size_t off = 0;
  auto take = [&](size_t bytes) -> void* {
    void* p = ws + off;
    off += (bytes + 255) & ~(size_t)255;
    return p;
  };
  f16* WO   = (f16*)take((size_t)E_ * E_ * 2);
  f16* AQ   = (f16*)take((size_t)M_ * E_ * 2);
  f16* AK   = (f16*)take((size_t)M_ * E_ * 2);
  f16* VH   = (f16*)take((size_t)M_ * E_ * 2);
  f16* QH   = (f16*)take((size_t)M_ * E_ * 2);
  f16* KH   = (f16*)take((size_t)M_ * E_ * 2);
  f16* AO   = (f16*)take((size_t)M_ * E_ * 2);
  float* XWQ  = (float*)take((size_t)M_ * G3_ * 4);
  float* XWK  = (float*)take((size_t)M_ * G3_ * 4);
  float* QPRE = (float*)take((size_t)M_ * E_ * 4);
  float* KPRE = (float*)take((size_t)M_ * E_ * 4);

  k_prep<<<dim3(M_), dim3(256), 0, stream>>>(x, tok, q_wih, k_wih, v_emb, VH, AQ, AK, XWQ, XWK);

  k_mega<<<dim3(521), dim3(256), 0, stream>>>(XWQ, XWK, q_whh, k_whh, AQ, AK,
                                              q_lin, k_lin, x, QPRE, KPRE, out_w, WO);

  k_fix<<<dim3(M_ / 128, E_ / 128, 2), dim3(256), 0, stream>>>(AQ, AK, q_lin, k_lin, QPRE, KPRE);
  k_ln<<<dim3(M_, 2), dim3(256), 0, stream>>>(QPRE, KPRE, q_ln_w, q_ln_b, k_ln_w, k_ln_b, QH, KH);

  k_attn<<<dim3(T_ / 64, B_ * H_), dim3(256), 0, stream>>>(QH, KH, VH, AO);
  k_gemm_out<<<dim3(M_ / 128, E_ / 128), dim3(256), 0, stream>>>(AO, WO, out_b, outp);
}

// Round 12
// 907.705 us; speedup vs baseline: 1.5453x; 1.0297x over previous
//
#include <hip/hip_runtime.h>

// R12: broadcast mechanism replaced. Evidence R6-R11: per-step cost invariant
// to MAC instr/deps/order => ~580cy fixed overhead = readlane broadcast + pack
// + 1-step prefetch L3-latency leak. Fix: h broadcast via LDS (1 ds_write_b16
// + 8 uniform ds_read_b128, conflict-free broadcast), weights re-paired
// (2i,2i+1); 2-step xw prefetch. Dots = R7's exact minimal form. All kernels
// except gru_core identical to R7 (best: 657us mega / 880us total).

namespace {

constexpr int B_ = 2, T_ = 2048, E_ = 1024, H_ = 16, HD_ = 64, G3_ = 192, M_ = B_ * T_;
constexpr float SRg = -1.4426950408889634f;  // -log2(e), r/z gates
constexpr float SNg = 2.8853900817779268f;   // 2*log2(e), n gate

typedef _Float16 f16;
typedef _Float16 f16x8 __attribute__((ext_vector_type(8)));
typedef _Float16 f16x4 __attribute__((ext_vector_type(4)));
typedef _Float16 f16x2 __attribute__((ext_vector_type(2)));
typedef float f32x4 __attribute__((ext_vector_type(4)));

__device__ __forceinline__ f32x4 mfma16(f16x8 a, f16x8 b, f32x4 c) {
  return __builtin_amdgcn_mfma_f32_16x16x32_f16(a, b, c, 0, 0, 0);
}

#if __has_builtin(__builtin_amdgcn_fdot2)
__device__ __forceinline__ float fdot2(f16x2 a, f16x2 b, float c) {
  return __builtin_amdgcn_fdot2(a, b, c, false);
}
#else
__device__ __forceinline__ float fdot2(f16x2 a, f16x2 b, float c) {
  return c + (float)a[0] * (float)b[0] + (float)a[1] * (float)b[1];
}
#endif

__device__ __forceinline__ float exp2_(float x) {
#if __has_builtin(__builtin_amdgcn_exp2f)
  return __builtin_amdgcn_exp2f(x);
#else
  return exp2f(x);
#endif
}
__device__ __forceinline__ float rcp_(float x) {
#if __has_builtin(__builtin_amdgcn_rcpf)
  return __builtin_amdgcn_rcpf(x);
#else
  return 1.f / x;
#endif
}

// stage a 128x64 f32 tile -> f16 LDS [128][72]; same thread mapping as f16 path
__device__ __forceinline__ void stage_w_f32(const float* __restrict__ Wf,
                                            f16 (*Bs)[72], int n0, int kt,
                                            int tid) {
#pragma unroll
  for (int it = 0; it < 4; ++it) {
    const int r = it * 32 + (tid >> 3);
    const int cs = (tid & 7) * 8;
    const float* src = Wf + (size_t)(n0 + r) * E_ + kt + cs;
    float4 w0 = *(const float4*)src;
    float4 w1 = *(const float4*)(src + 4);
    f16x8 o = {(f16)w0.x, (f16)w0.y, (f16)w0.z, (f16)w0.w,
               (f16)w1.x, (f16)w1.y, (f16)w1.z, (f16)w1.w};
    *(f16x8*)&Bs[r][cs] = o;
  }
}

// ---------------- prep: v = silu(x)*emb, x_proj pooling, xw = pool16(x)@wih^T
__global__ __launch_bounds__(256) void k_prep(
    const float* __restrict__ x, const int* __restrict__ tok,
    const float* __restrict__ wihq, const float* __restrict__ wihk,
    const float* __restrict__ v_emb,
    f16* __restrict__ vh, f16* __restrict__ aq, f16* __restrict__ ak,
    float* __restrict__ xwq, float* __restrict__ xwk) {
  __shared__ float xs[E_];
  __shared__ float xp[64];
  const int row = blockIdx.x;
  const int b = row >> 11, t = row & (T_ - 1);
  const int tid = threadIdx.x;
  const float* xrow = x + (size_t)row * E_;
  {
    const int tk = tok[row];
    float4 xv = ((const float4*)xrow)[tid];
    ((float4*)xs)[tid] = xv;
    float4 ev = ((const float4*)(v_emb + (size_t)tk * E_))[tid];
    f16x4 o;
    o[0] = (f16)(xv.x / (1.f + __expf(-xv.x)) * ev.x);
    o[1] = (f16)(xv.y / (1.f + __expf(-xv.y)) * ev.y);
    o[2] = (f16)(xv.z / (1.f + __expf(-xv.z)) * ev.z);
    o[3] = (f16)(xv.w / (1.f + __expf(-xv.w)) * ev.w);
    const int e0 = tid * 4;
    const size_t voff = ((size_t)(b * H_ + (e0 >> 6)) * T_ + t) * HD_ + (e0 & 63);
    *(f16x4*)(vh + voff) = o;
  }
  __syncthreads();
  if (tid < 64) {
    float s = 0.f;
#pragma unroll
    for (int j = 0; j < 16; ++j) s += xs[tid * 16 + j];
    xp[tid] = s * (1.f / 16.f);
  }
  for (int i = tid; i < 960; i += 256) {
    int s0 = (i * 1024) / 960;
    int e0 = ((i + 1) * 1024 + 959) / 960;
    float m = xs[s0];
    if (e0 - s0 == 2) m = (m + xs[s0 + 1]) * 0.5f;
    f16 hv = (f16)m;
    aq[(size_t)row * E_ + 64 + i] = hv;
    ak[(size_t)row * E_ + 64 + i] = hv;
  }
  __syncthreads();
  for (int o = tid; o < 2 * G3_; o += 256) {
    const int chain = o / G3_, g = o % G3_;
    const float* wrow = (chain ? wihk : wihq) + (size_t)g * 64;
    float acc = 0.f;
#pragma unroll
    for (int c = 0; c < 16; ++c) {
      float4 wv = *(const float4*)(wrow + c * 4);
      acc += xp[c * 4] * wv.x + xp[c * 4 + 1] * wv.y +
             xp[c * 4 + 2] * wv.z + xp[c * 4 + 3] * wv.w;
    }
    const float sc = (g < 128) ? SRg : SNg;
    (chain ? xwk : xwq)[(size_t)row * G3_ + g] = acc * sc;
  }
}

// ---------------- GRU core: one wave, lane j owns h_j -----------------------
// h broadcast via LDS: lane writes f16(h) (ds_write_b16); wave re-reads all 64
// h as 8 uniform-address ds_read_b128 (broadcast, conflict-free). No readlane,
// no permlane pack. Weights paired (2i,2i+1). 2-step xw prefetch.
__device__ __forceinline__ void gru_core(const float* __restrict__ xw,
                                         const float* __restrict__ whh,
                                         f16* __restrict__ a, int lane,
                                         f16* __restrict__ hbuf) {
  __builtin_amdgcn_s_setprio(3);
  f16x2 wr[32], wz[32], wn[32];
#pragma unroll
  for (int i = 0; i < 32; ++i) {
    wr[i] = {(f16)(whh[(size_t)lane * 64 + 2 * i] * SRg),
             (f16)(whh[(size_t)lane * 64 + 2 * i + 1] * SRg)};
    wz[i] = {(f16)(whh[(size_t)(64 + lane) * 64 + 2 * i] * SRg),
             (f16)(whh[(size_t)(64 + lane) * 64 + 2 * i + 1] * SRg)};
    wn[i] = {(f16)(whh[(size_t)(128 + lane) * 64 + 2 * i] * SNg),
             (f16)(whh[(size_t)(128 + lane) * 64 + 2 * i + 1] * SNg)};
  }
  float h = 0.f;
  hbuf[lane] = (f16)0.f;  // init broadcast buffer
  // 2-step xw prefetch pipeline (covers ~900cy L3 latency at short steps)
  float xr = xw[lane], xz = xw[64 + lane], xn = xw[128 + lane];
  const float* n1p = xw + G3_;
  float pr1 = n1p[lane], pz1 = n1p[64 + lane], pn1 = n1p[128 + lane];
  f16* ap = a + lane;
  for (int t = 0; t < T_; ++t) {
    // broadcast: 8 uniform-address 16B LDS reads -> all 64 h values
    f16x8 hv0 = *(const f16x8*)(hbuf);
    f16x8 hv1 = *(const f16x8*)(hbuf + 8);
    f16x8 hv2 = *(const f16x8*)(hbuf + 16);
    f16x8 hv3 = *(const f16x8*)(hbuf + 24);
    f16x8 hv4 = *(const f16x8*)(hbuf + 32);
    f16x8 hv5 = *(const f16x8*)(hbuf + 40);
    f16x8 hv6 = *(const f16x8*)(hbuf + 48);
    f16x8 hv7 = *(const f16x8*)(hbuf + 56);
    // prefetch t+2
    const int tn = (t + 2 < T_) ? t + 2 : T_ - 1;
    const float* nx = xw + (size_t)tn * G3_;
    const float pr2 = nx[lane], pz2 = nx[64 + lane], pn2 = nx[128 + lane];
#define PAIR(v, p) (f16x2{(v)[2 * (p)], (v)[2 * (p) + 1]})
#define GATEDOT(acc, w)                                  \
  {                                                      \
    _Pragma("unroll") for (int p = 0; p < 4; ++p) {      \
      acc = fdot2(w[p], PAIR(hv0, p), acc);              \
      acc = fdot2(w[4 + p], PAIR(hv1, p), acc);          \
      acc = fdot2(w[8 + p], PAIR(hv2, p), acc);          \
      acc = fdot2(w[12 + p], PAIR(hv3, p), acc);         \
      acc = fdot2(w[16 + p], PAIR(hv4, p), acc);         \
      acc = fdot2(w[20 + p], PAIR(hv5, p), acc);         \
      acc = fdot2(w[24 + p], PAIR(hv6, p), acc);         \
      acc = fdot2(w[28 + p], PAIR(hv7, p), acc);         \
    }                                                    \
  }
    float ar = xr;
    GATEDOT(ar, wr);
    const float r = rcp_(1.f + exp2_(ar));
    float an = 0.f;
    GATEDOT(an, wn);
    const float p2 = fmaf(r, an, xn);
    const float n = fmaf(-2.f, rcp_(1.f + exp2_(p2)), 1.f);  // tanh
    float az = xz;
    GATEDOT(az, wz);
    const float z = rcp_(1.f + exp2_(az));
    h = fmaf(z, h - n, n);
#undef GATEDOT
#undef PAIR
    const f16 h16 = (f16)h;
    ap[(size_t)t * E_] = h16;
    hbuf[lane] = h16;  // next step's broadcast source
    xr = pr1; xz = pz1; xn = pn1;
    pr1 = pr2; pz1 = pz2; pn1 = pn2;
  }
}

// ---------------- megakernel: GRU (block 0) + QK partial GEMMs (+x) + WO cvt
__global__ __launch_bounds__(256, 1) void k_mega(
    const float* __restrict__ xwq, const float* __restrict__ xwk,
    const float* __restrict__ whhq, const float* __restrict__ whhk,
    f16* __restrict__ aq, f16* __restrict__ ak,
    const float* __restrict__ WQf, const float* __restrict__ WKf,
    const float* __restrict__ x,
    float* __restrict__ QPRE, float* __restrict__ KPRE,
    const float* __restrict__ out_w, f16* __restrict__ WO) {
  __shared__ __align__(16) f16 As[128][72];
  __shared__ __align__(16) f16 Bs[128][72];
  const int bx = blockIdx.x;
  const int tid = threadIdx.x;
  if (bx == 0) {
    const int wid = tid >> 6, lane = tid & 63;
    const int qk = wid >> 1, b = wid & 1;
    const float* xw = (qk ? xwk : xwq) + (size_t)b * T_ * G3_;
    const float* whh = qk ? whhk : whhq;
    f16* a = (qk ? ak : aq) + (size_t)b * T_ * E_;
    f16* hbuf = &As[0][0] + wid * 64;  // 128B-aligned per-wave h buffer
    gru_core(xw, whh, a, lane, hbuf);
    return;
  }
  if (bx <= 512) {
    const int bid = bx - 1;
    const int chain = bid >> 8, tile = bid & 255;
    const int m0 = (tile >> 3) * 128, n0 = (tile & 7) * 128;
    const f16* A = chain ? ak : aq;
    const float* Wf = chain ? WKf : WQf;
    float* C = chain ? KPRE : QPRE;
    const int wid = tid >> 6, lane = tid & 63;
    const int wr = wid >> 1, wc = wid & 1;
    const int lg = lane >> 4, lc = lane & 15;
    f32x4 acc[4][4] = {};
    for (int kt = 64; kt < E_; kt += 64) {
#pragma unroll
      for (int it = 0; it < 4; ++it) {
        const int r = it * 32 + (tid >> 3);
        const int cs = (tid & 7) * 8;
        *(f16x8*)&As[r][cs] = *(const f16x8*)(A + (size_t)(m0 + r) * E_ + kt + cs);
      }
      stage_w_f32(Wf, Bs, n0, kt, tid);
      __syncthreads();
      f16x8 af[4][2], bf[4][2];
#pragma unroll
      for (int mi = 0; mi < 4; ++mi)
#pragma unroll
        for (int ks = 0; ks < 2; ++ks) {
          af[mi][ks] = *(const f16x8*)&As[wr * 64 + mi * 16 + lc][ks * 32 + lg * 8];
          bf[mi][ks] = *(const f16x8*)&Bs[wc * 64 + mi * 16 + lc][ks * 32 + lg * 8];
        }
#pragma unroll
      for (int mi = 0; mi < 4; ++mi)
#pragma unroll
        for (int ni = 0; ni < 4; ++ni)
#pragma unroll
          for (int ks = 0; ks < 2; ++ks)
            acc[mi][ni] = mfma16(af[mi][ks], bf[ni][ks], acc[mi][ni]);
      __syncthreads();
    }
#pragma unroll
    for (int mi = 0; mi < 4; ++mi) {
      const int r0 = m0 + wr * 64 + mi * 16 + lg * 4;
#pragma unroll
      for (int ni = 0; ni < 4; ++ni) {
        const int col = n0 + wc * 64 + ni * 16 + lc;
#pragma unroll
        for (int q = 0; q < 4; ++q) {
          const size_t idx = (size_t)(r0 + q) * E_ + col;
          C[idx] = acc[mi][ni][q] + x[idx];
        }
      }
    }
    return;
  }
  {
    const int cb = bx - 513;
    for (int i = cb * 256 + tid; i < E_ * E_ / 4; i += 8 * 256) {
      float4 v = ((const float4*)out_w)[i];
      f16x4 o = {(f16)v.x, (f16)v.y, (f16)v.z, (f16)v.w};
      *(f16x4*)(WO + (size_t)i * 4) = o;
    }
  }
}

// ---------------- fix: C += A[:,0:64] @ W[:,0:64]^T -------------------------
__global__ __launch_bounds__(256) void k_fix(
    const f16* __restrict__ aq, const f16* __restrict__ ak,
    const float* __restrict__ WQf, const float* __restrict__ WKf,
    float* __restrict__ QPRE, float* __restrict__ KPRE) {
  __shared__ __align__(16) f16 As[128][72];
  __shared__ __align__(16) f16 Bs[128][72];
  const int chain = blockIdx.z;
  const f16* A = chain ? ak : aq;
  const float* Wf = chain ? WKf : WQf;
  float* C = chain ? KPRE : QPRE;
  const int m0 = blockIdx.x * 128, n0 = blockIdx.y * 128;
  const int tid = threadIdx.x;
  const int wid = tid >> 6, lane = tid & 63;
  const int wr = wid >> 1, wc = wid & 1;
  const int lg = lane >> 4, lc = lane & 15;
#pragma unroll
  for (int it = 0; it < 4; ++it) {
    const int r = it * 32 + (tid >> 3);
    const int cs = (tid & 7) * 8;
    *(f16x8*)&As[r][cs] = *(const f16x8*)(A + (size_t)(m0 + r) * E_ + cs);
  }
  stage_w_f32(Wf, Bs, n0, 0, tid);
  __syncthreads();
  f32x4 acc[4][4] = {};
  f16x8 af[4][2], bf[4][2];
#pragma unroll
  for (int mi = 0; mi < 4; ++mi)
#pragma unroll
    for (int ks = 0; ks < 2; ++ks) {
      af[mi][ks] = *(const f16x8*)&As[wr * 64 + mi * 16 + lc][ks * 32 + lg * 8];
      bf[mi][ks] = *(const f16x8*)&Bs[wc * 64 + mi * 16 + lc][ks * 32 + lg * 8];
    }
#pragma unroll
  for (int mi = 0; mi < 4; ++mi)
#pragma unroll
    for (int ni = 0; ni < 4; ++ni)
#pragma unroll
      for (int ks = 0; ks < 2; ++ks)
        acc[mi][ni] = mfma16(af[mi][ks], bf[ni][ks], acc[mi][ni]);
#pragma unroll
  for (int mi = 0; mi < 4; ++mi) {
    const int r0 = m0 + wr * 64 + mi * 16 + lg * 4;
#pragma unroll
    for (int ni = 0; ni < 4; ++ni) {
      const int col = n0 + wc * 64 + ni * 16 + lc;
#pragma unroll
      for (int q = 0; q < 4; ++q) {
        const size_t idx = (size_t)(r0 + q) * E_ + col;
        C[idx] += acc[mi][ni][q];
      }
    }
  }
}

// ---------------- LayerNorm (both chains), write f16 in [B,H,T,HD] ---------
__global__ __launch_bounds__(256) void k_ln(
    const float* __restrict__ qpre, const float* __restrict__ kpre,
    const float* __restrict__ qw, const float* __restrict__ qb,
    const float* __restrict__ kw, const float* __restrict__ kb,
    f16* __restrict__ qh, f16* __restrict__ kh) {
  const int chain = blockIdx.y;
  const float* pre = chain ? kpre : qpre;
  const float* gw = chain ? kw : qw;
  const float* gb = chain ? kb : qb;
  f16* outp = chain ? kh : qh;
  const int row = blockIdx.x;
  const int tid = threadIdx.x;
  const float4 v = ((const float4*)(pre + (size_t)row * E_))[tid];
  float s = v.x + v.y + v.z + v.w;
  float s2 = v.x * v.x + v.y * v.y + v.z * v.z + v.w * v.w;
#pragma unroll
  for (int off = 32; off; off >>= 1) {
    s += __shfl_xor(s, off);
    s2 += __shfl_xor(s2, off);
  }
  __shared__ float red[8];
  const int wid = tid >> 6, lane = tid & 63;
  if (!lane) { red[wid] = s; red[4 + wid] = s2; }
  __syncthreads();
  s = red[0] + red[1] + red[2] + red[3];
  s2 = red[4] + red[5] + red[6] + red[7];
  const float mu = s * (1.f / E_);
  const float inv = rsqrtf(s2 * (1.f / E_) - mu * mu + 1e-5f);
  const float4 w4 = ((const float4*)gw)[tid];
  const float4 b4 = ((const float4*)gb)[tid];
  const int e0 = tid * 4;
  f16x4 o;
  o[0] = (f16)((v.x - mu) * inv * w4.x + b4.x);
  o[1] = (f16)((v.y - mu) * inv * w4.y + b4.y);
  o[2] = (f16)((v.z - mu) * inv * w4.z + b4.z);
  o[3] = (f16)((v.w - mu) * inv * w4.w + b4.w);
  const int b = row >> 11, t = row & (T_ - 1);
  const size_t off2 = ((size_t)(b * H_ + (e0 >> 6)) * T_ + t) * HD_ + (e0 & 63);
  *(f16x4*)(outp + off2) = o;
}

// ---------------- flash attention: causal, scores*2/sqrt(64) = *0.25 -------
__global__ __launch_bounds__(256) void k_attn(const f16* __restrict__ Q,
                                              const f16* __restrict__ K,
                                              const f16* __restrict__ V,
                                              f16* __restrict__ AO) {
  __shared__ __align__(16) f16 Kt[64][72];
  __shared__ __align__(16) f16 Vt[64][72];
  __shared__ __align__(16) f16 Ps[4][16][72];
  const int qi = blockIdx.x, bh = blockIdx.y;
  const int b = bh >> 4, h = bh & 15;
  const int tid = threadIdx.x, wid = tid >> 6, lane = tid & 63;
  const int lg = lane >> 4, lc = lane & 15;
  const size_t hbase = (size_t)bh * T_ * HD_;
  const int qb = qi * 64;
  f16x8 qf[2];
  {
    const int qrow = qb + wid * 16 + lc;
#pragma unroll
    for (int ks = 0; ks < 2; ++ks)
      qf[ks] = *(const f16x8*)(Q + hbase + (size_t)qrow * HD_ + ks * 32 + lg * 8);
  }
  f32x4 o[4] = {};
  float m_run[4] = {-1e30f, -1e30f, -1e30f, -1e30f};
  float l_run[4] = {};
  const int qrow_d = qb + wid * 16 + lg * 4;
  for (int kt = 0; kt <= qi; ++kt) {
    {
      const int r = tid >> 2, cs = (tid & 3) * 16;
      const f16* ksrc = K + hbase + (size_t)(kt * 64 + r) * HD_ + cs;
      *(f16x8*)&Kt[r][cs] = *(const f16x8*)ksrc;
      *(f16x8*)&Kt[r][cs + 8] = *(const f16x8*)(ksrc + 8);
      const f16* vsrc = V + hbase + (size_t)(kt * 64 + lane) * HD_ + wid * 16;
      f16x8 va = *(const f16x8*)vsrc;
      f16x8 vb = *(const f16x8*)(vsrc + 8);
#pragma unroll
      for (int u = 0; u < 8; ++u) {
        Vt[wid * 16 + u][lane] = va[u];
        Vt[wid * 16 + 8 + u][lane] = vb[u];
      }
    }
    __syncthreads();
    f32x4 s[4] = {};
#pragma unroll
    for (int nt = 0; nt < 4; ++nt)
#pragma unroll
      for (int ks = 0; ks < 2; ++ks) {
        f16x8 kf = *(const f16x8*)&Kt[nt * 16 + lc][ks * 32 + lg * 8];
        s[nt] = mfma16(qf[ks], kf, s[nt]);
      }
    const bool diag = (kt == qi);
#pragma unroll
    for (int nt = 0; nt < 4; ++nt) {
      const int colg = kt * 64 + nt * 16 + lc;
#pragma unroll
      for (int r = 0; r < 4; ++r) {
        float v = s[nt][r] * 0.25f;
        if (diag && colg > qrow_d + r) v = -1e30f;
        s[nt][r] = v;
      }
    }
    float scalev[4];
#pragma unroll
    for (int r = 0; r < 4; ++r) {
      float m = fmaxf(fmaxf(s[0][r], s[1][r]), fmaxf(s[2][r], s[3][r]));
#pragma unroll
      for (int of = 1; of < 16; of <<= 1) m = fmaxf(m, __shfl_xor(m, of));
      const float mn = fmaxf(m_run[r], m);
      scalev[r] = __expf(m_run[r] - mn);
      m_run[r] = mn;
    }
    float ladd[4] = {};
#pragma unroll
    for (int nt = 0; nt < 4; ++nt)
#pragma unroll
      for (int r = 0; r < 4; ++r) {
        const float p = __expf(s[nt][r] - m_run[r]);
        s[nt][r] = p;
        ladd[r] += p;
      }
#pragma unroll
    for (int r = 0; r < 4; ++r) {
      float la = ladd[r];
#pragma unroll
      for (int of = 1; of < 16; of <<= 1) la += __shfl_xor(la, of);
      l_run[r] = l_run[r] * scalev[r] + la;
      o[0][r] *= scalev[r];
      o[1][r] *= scalev[r];
      o[2][r] *= scalev[r];
      o[3][r] *= scalev[r];
    }
#pragma unroll
    for (int nt = 0; nt < 4; ++nt)
#pragma unroll
      for (int r = 0; r < 4; ++r)
        Ps[wid][lg * 4 + r][nt * 16 + lc] = (f16)s[nt][r];
    f16x8 pf[2];
#pragma unroll
    for (int ks = 0; ks < 2; ++ks)
      pf[ks] = *(const f16x8*)&Ps[wid][lc][ks * 32 + lg * 8];
#pragma unroll
    for (int nt = 0; nt < 4; ++nt)
#pragma unroll
      for (int ks = 0; ks < 2; ++ks) {
        f16x8 vf = *(const f16x8*)&Vt[nt * 16 + lc][ks * 32 + lg * 8];
        o[nt] = mfma16(pf[ks], vf, o[nt]);
      }
    __syncthreads();
  }
#pragma unroll
  for (int nt = 0; nt < 4; ++nt)
#pragma unroll
    for (int r = 0; r < 4; ++r) {
      const float val = o[nt][r] / l_run[r];
      const int qrow = qrow_d + r;
      AO[((size_t)(b * T_ + qrow)) * E_ + h * HD_ + nt * 16 + lc] = (f16)val;
    }
}

// ---------------- out GEMM: C = A @ WO^T + bias -----------------------------
__global__ __launch_bounds__(256) void k_gemm_out(
    const f16* __restrict__ A, const f16* __restrict__ W,
    const float* __restrict__ bias, float* __restrict__ C) {
  __shared__ __align__(16) f16 As[128][72];
  __shared__ __align__(16) f16 Bs[128][72];
  const int m0 = blockIdx.x * 128, n0 = blockIdx.y * 128;
  const int tid = threadIdx.x;
  const int wid = tid >> 6, lane = tid & 63;
  const int wr = wid >> 1, wc = wid & 1;
  const int lg = lane >> 4, lc = lane & 15;
  f32x4 acc[4][4] = {};
  for (int kt = 0; kt < E_; kt += 64) {
#pragma unroll
    for (int it = 0; it < 4; ++it) {
      const int r = it * 32 + (tid >> 3);
      const int cs = (tid & 7) * 8;
      *(f16x8*)&As[r][cs] = *(const f16x8*)(A + (size_t)(m0 + r) * E_ + kt + cs);
      *(f16x8*)&Bs[r][cs] = *(const f16x8*)(W + (size_t)(n0 + r) * E_ + kt + cs);
    }
    __syncthreads();
    f16x8 af[4][2], bf[4][2];
#pragma unroll
    for (int mi = 0; mi < 4; ++mi)
#pragma unroll
      for (int ks = 0; ks < 2; ++ks) {
        af[mi][ks] = *(const f16x8*)&As[wr * 64 + mi * 16 + lc][ks * 32 + lg * 8];
        bf[mi][ks] = *(const f16x8*)&Bs[wc * 64 + mi * 16 + lc][ks * 32 + lg * 8];
      }
#pragma unroll
    for (int mi = 0; mi < 4; ++mi)
#pragma unroll
      for (int ni = 0; ni < 4; ++ni)
#pragma unroll
        for (int ks = 0; ks < 2; ++ks)
          acc[mi][ni] = mfma16(af[mi][ks], bf[ni][ks], acc[mi][ni]);
    __syncthreads();
  }
#pragma unroll
  for (int mi = 0; mi < 4; ++mi) {
    const int r0 = m0 + wr * 64 + mi * 16 + lg * 4;
#pragma unroll
    for (int ni = 0; ni < 4; ++ni) {
      const int col = n0 + wc * 64 + ni * 16 + lc;
      const float bv = bias[col];
#pragma unroll
      for (int q = 0; q < 4; ++q)
        C[(size_t)(r0 + q) * E_ + col] = acc[mi][ni][q] + bv;
    }
  }
}

}  // namespace

extern "C" void kernel_launch(void* const* d_in, const int* in_sizes, int n_in,
                              void* d_out, int out_size, void* d_ws, size_t ws_size,
                              hipStream_t stream) {
  (void)in_sizes; (void)n_in; (void)out_size; (void)ws_size;
  const float* x      = (const float*)d_in[0];
  const int*   tok    = (const int*)d_in[1];
  const float* q_wih  = (const float*)d_in[2];
  const float* q_whh  = (const float*)d_in[3];
  const float* q_lin  = (const float*)d_in[4];
  const float* k_wih  = (const float*)d_in[5];
  const float* k_whh  = (const float*)d_in[6];
  const float* k_lin  = (const float*)d_in[7];
  const float* v_emb  = (const float*)d_in[8];
  const float* q_ln_w = (const float*)d_in[9];
  const float* q_ln_b = (const float*)d_in[10];
  const float* k_ln_w = (const float*)d_in[11];
  const float* k_ln_b = (const float*)d_in[12];
  const float* out_w  = (const float*)d_in[13];
  const float* out_b  = (const float*)d_in[14];
  float* outp = (float*)d_out;

  char* ws = (char*)d_ws;
  size_t off = 0;
  auto take = [&](size_t bytes) -> void* {
    void* p = ws + off;
    off += (bytes + 255) & ~(size_t)255;
    return p;
  };
  f16* WO   = (f16*)take((size_t)E_ * E_ * 2);
  f16* AQ   = (f16*)take((size_t)M_ * E_ * 2);
  f16* AK   = (f16*)take((size_t)M_ * E_ * 2);
  f16* VH   = (f16*)take((size_t)M_ * E_ * 2);
  f16* QH   = (f16*)take((size_t)M_ * E_ * 2);
  f16* KH   = (f16*)take((size_t)M_ * E_ * 2);
  f16* AO   = (f16*)take((size_t)M_ * E_ * 2);
  float* XWQ  = (float*)take((size_t)M_ * G3_ * 4);
  float* XWK  = (float*)take((size_t)M_ * G3_ * 4);
  float* QPRE = (float*)take((size_t)M_ * E_ * 4);
  float* KPRE = (float*)take((size_t)M_ * E_ * 4);

  k_prep<<<dim3(M_), dim3(256), 0, stream>>>(x, tok, q_wih, k_wih, v_emb, VH, AQ, AK, XWQ, XWK);

  k_mega<<<dim3(521), dim3(256), 0, stream>>>(XWQ, XWK, q_whh, k_whh, AQ, AK,
                                              q_lin, k_lin, x, QPRE, KPRE, out_w, WO);

  k_fix<<<dim3(M_ / 128, E_ / 128, 2), dim3(256), 0, stream>>>(AQ, AK, q_lin, k_lin, QPRE, KPRE);
  k_ln<<<dim3(M_, 2), dim3(256), 0, stream>>>(QPRE, KPRE, q_ln_w, q_ln_b, k_ln_w, k_ln_b, QH, KH);

  k_attn<<<dim3(T_ / 64, B_ * H_), dim3(256), 0, stream>>>(QH, KH, VH, AO);
  k_gemm_out<<<dim3(M_ / 128, E_ / 128), dim3(256), 0, stream>>>(AO, WO, out_b, outp);
}